// Round 1
// baseline (341.620 us; speedup 1.0000x reference)
//
#include <hip/hip_runtime.h>
#include <hip/hip_bf16.h>

// Problem constants
#define BB 8
#define TT 4096
#define FF 256
#define BT 32768   // BB*TT

typedef unsigned short u16;
typedef __attribute__((ext_vector_type(8))) short short8;
typedef __attribute__((ext_vector_type(4))) float f32x4;
typedef __attribute__((ext_vector_type(4))) unsigned int u32x4;

static __device__ __forceinline__ float bf2f(u16 u) {
    union { unsigned int i; float f; } v; v.i = ((unsigned int)u) << 16; return v.f;
}
static __device__ __forceinline__ u16 f2bf(float f) {
    union { float f; unsigned int i; } v; v.f = f;
    unsigned int x = v.i;
    return (u16)((x + 0x7fffu + ((x >> 16) & 1u)) >> 16);  // RNE
}

// ---------------------------------------------------------------------------
// exp_w: per-row max then exp(w - max) -> bf16 [T][T]
// ---------------------------------------------------------------------------
__global__ __launch_bounds__(256) void expw_kernel(const float* __restrict__ w,
                                                   u16* __restrict__ ew) {
    __shared__ float red[256];
    int row = blockIdx.x;
    int tid = threadIdx.x;
    const float* wr = w + (size_t)row * TT;

    f32x4 vals[4];
    float m = -1e30f;
#pragma unroll
    for (int v = 0; v < 4; ++v) {
        int idx = (v * 256 + tid) * 4;
        vals[v] = *(const f32x4*)(wr + idx);
#pragma unroll
        for (int j = 0; j < 4; ++j) m = fmaxf(m, vals[v][j]);
    }
    red[tid] = m;
    __syncthreads();
    for (int s = 128; s > 0; s >>= 1) {
        if (tid < s) red[tid] = fmaxf(red[tid], red[tid + s]);
        __syncthreads();
    }
    float rm = red[0];
#pragma unroll
    for (int v = 0; v < 4; ++v) {
        int idx = (v * 256 + tid) * 4;
        float e0 = expf(vals[v][0] - rm), e1 = expf(vals[v][1] - rm);
        float e2 = expf(vals[v][2] - rm), e3 = expf(vals[v][3] - rm);
        uint2 pk;
        pk.x = (unsigned int)f2bf(e0) | ((unsigned int)f2bf(e1) << 16);
        pk.y = (unsigned int)f2bf(e2) | ((unsigned int)f2bf(e3) << 16);
        *(uint2*)(ew + (size_t)row * TT + idx) = pk;
    }
}

// ---------------------------------------------------------------------------
// generic f32 -> bf16 cast, 4 elems/thread
// ---------------------------------------------------------------------------
__global__ __launch_bounds__(256) void cvt_bf16_kernel(const float* __restrict__ in,
                                                       u16* __restrict__ out, int n4) {
    int i = blockIdx.x * 256 + threadIdx.x;
    if (i < n4) {
        f32x4 v = ((const f32x4*)in)[i];
        uint2 pk;
        pk.x = (unsigned int)f2bf(v[0]) | ((unsigned int)f2bf(v[1]) << 16);
        pk.y = (unsigned int)f2bf(v[2]) | ((unsigned int)f2bf(v[3]) << 16);
        ((uint2*)out)[i] = pk;
    }
}

// ---------------------------------------------------------------------------
// NT GEMM: C[M,N] = A[M,K] * B[N,K]^T (+bias over N), bf16 in, f32 acc.
// 128x128 tile, BK=32, 4 waves (2x2), each wave 64x64 via 4x4 of 16x16x32 MFMA.
// MODE 0: f32 out (+bias if non-null); 1: sigmoid -> bf16; 2: (+bias) -> bf16
// ---------------------------------------------------------------------------
template <int MODE>
__global__ __launch_bounds__(256) void gemm_nt(const u16* __restrict__ Aall,
                                               const u16* __restrict__ Ball,
                                               const float* __restrict__ bias,
                                               void* __restrict__ Call,
                                               int M, int N, int K,
                                               long long strideA, long long strideB,
                                               long long strideC) {
    __shared__ u16 As[128][40];   // +8 pad: 80B row stride, 16B aligned
    __shared__ u16 Bs[128][40];

    const u16* A = Aall + (size_t)blockIdx.z * strideA;
    const u16* Bm = Ball + (size_t)blockIdx.z * strideB;

    int tid = threadIdx.x;
    int lane = tid & 63;
    int w = tid >> 6;
    int wr = w >> 1, wc = w & 1;
    int fr = lane & 15, kg = lane >> 4;

    f32x4 acc[4][4];
#pragma unroll
    for (int m = 0; m < 4; ++m)
#pragma unroll
        for (int n = 0; n < 4; ++n) acc[m][n] = (f32x4){0.f, 0.f, 0.f, 0.f};

    int bm = blockIdx.x, bn = blockIdx.y;
    int nk = K >> 5;

    for (int kt = 0; kt < nk; ++kt) {
        __syncthreads();
#pragma unroll
        for (int rep = 0; rep < 2; ++rep) {
            int v = tid + rep * 256;      // 0..511
            int row = v >> 2, ch = (v & 3) << 3;
            *(u32x4*)&As[row][ch] =
                *(const u32x4*)(A + (size_t)(bm * 128 + row) * K + (kt << 5) + ch);
            *(u32x4*)&Bs[row][ch] =
                *(const u32x4*)(Bm + (size_t)(bn * 128 + row) * K + (kt << 5) + ch);
        }
        __syncthreads();
        short8 af[4], bfr[4];
#pragma unroll
        for (int m = 0; m < 4; ++m) af[m] = *(const short8*)&As[wr * 64 + m * 16 + fr][kg * 8];
#pragma unroll
        for (int n = 0; n < 4; ++n) bfr[n] = *(const short8*)&Bs[wc * 64 + n * 16 + fr][kg * 8];
#pragma unroll
        for (int m = 0; m < 4; ++m)
#pragma unroll
            for (int n = 0; n < 4; ++n)
                acc[m][n] = __builtin_amdgcn_mfma_f32_16x16x32_bf16(af[m], bfr[n], acc[m][n], 0, 0, 0);
    }

    int row0 = bm * 128 + wr * 64;
    int col0 = bn * 128 + wc * 64;
    size_t cbase = (size_t)blockIdx.z * strideC;
#pragma unroll
    for (int n = 0; n < 4; ++n) {
        int col = col0 + n * 16 + fr;
        float bv = bias ? bias[col] : 0.0f;
#pragma unroll
        for (int m = 0; m < 4; ++m) {
            int rbase = row0 + m * 16 + kg * 4;
#pragma unroll
            for (int i = 0; i < 4; ++i) {
                float val = acc[m][n][i] + bv;
                size_t idx = cbase + (size_t)(rbase + i) * N + col;
                if (MODE == 0)
                    ((float*)Call)[idx] = val;
                else if (MODE == 1)
                    ((u16*)Call)[idx] = f2bf(1.0f / (1.0f + expf(-val)));
                else
                    ((u16*)Call)[idx] = f2bf(val);
            }
        }
    }
}

// ---------------------------------------------------------------------------
// Build Mt[b][512][T]: row 2f = expK*V feature f, row 2f+1 = expK feature f
// (exp over feature-dim max per (b,s) row). 64 s-rows per block.
// ---------------------------------------------------------------------------
__global__ __launch_bounds__(256) void build_mt(const u16* __restrict__ Kraw,
                                                const u16* __restrict__ Vraw,
                                                u16* __restrict__ Mt) {
    __shared__ u16 Ks[64][264];
    __shared__ u16 Vs[64][264];
    __shared__ float part[64][4];
    __shared__ float rmax[64];

    int s0 = blockIdx.x * 64;
    int b = blockIdx.y;
    int tid = threadIdx.x;
    size_t base = ((size_t)b * TT + s0) * FF;

#pragma unroll
    for (int v = 0; v < 8; ++v) {
        int i = v * 256 + tid;       // 0..2047 vectors of 8
        int row = i >> 5;
        int cb = (i & 31) << 3;
        *(u32x4*)&Ks[row][cb] = *(const u32x4*)(Kraw + base + (size_t)row * FF + cb);
        *(u32x4*)&Vs[row][cb] = *(const u32x4*)(Vraw + base + (size_t)row * FF + cb);
    }
    __syncthreads();
    {
        int row = tid >> 2, p = tid & 3;
        float m = -1e30f;
        for (int c = p * 64; c < p * 64 + 64; ++c) m = fmaxf(m, bf2f(Ks[row][c]));
        part[row][p] = m;
    }
    __syncthreads();
    if (tid < 64)
        rmax[tid] = fmaxf(fmaxf(part[tid][0], part[tid][1]), fmaxf(part[tid][2], part[tid][3]));
    __syncthreads();

    int f = tid >> 5;
    int lane = tid & 31;
    int sl = lane << 1;
    size_t mtb = (size_t)b * 512 * TT;
    for (int fb = 0; fb < 256; fb += 8) {
        int fi = fb + f;
        float ek0 = expf(bf2f(Ks[sl][fi]) - rmax[sl]);
        float ek1 = expf(bf2f(Ks[sl + 1][fi]) - rmax[sl + 1]);
        float nm0 = ek0 * bf2f(Vs[sl][fi]);
        float nm1 = ek1 * bf2f(Vs[sl + 1][fi]);
        unsigned int pn = (unsigned int)f2bf(nm0) | ((unsigned int)f2bf(nm1) << 16);
        unsigned int pd = (unsigned int)f2bf(ek0) | ((unsigned int)f2bf(ek1) << 16);
        *(unsigned int*)(Mt + mtb + (size_t)(2 * fi) * TT + s0 + sl) = pn;
        *(unsigned int*)(Mt + mtb + (size_t)(2 * fi + 1) * TT + s0 + sl) = pd;
    }
}

// ---------------------------------------------------------------------------
// Yt = sigmoid(Q) * num/den  (Qsig already sigmoided, bf16)
// G layout: [BT][512] f32, cols 2f = num, 2f+1 = den
// ---------------------------------------------------------------------------
__global__ __launch_bounds__(256) void epilogue_kernel(const u16* __restrict__ Qsig,
                                                       const float* __restrict__ G,
                                                       u16* __restrict__ Yt) {
    size_t total = (size_t)BT * FF;
    for (size_t i = (size_t)blockIdx.x * 256 + threadIdx.x; i < total;
         i += (size_t)gridDim.x * 256) {
        size_t r = i >> 8;
        int f = (int)(i & 255);
        float2 g = *(const float2*)(G + r * 512 + 2 * f);
        float q = bf2f(Qsig[i]);
        Yt[i] = f2bf(q * g.x / g.y);
    }
}

// ---------------------------------------------------------------------------
extern "C" void kernel_launch(void* const* d_in, const int* in_sizes, int n_in,
                              void* d_out, int out_size, void* d_ws, size_t ws_size,
                              hipStream_t stream) {
    const float* x  = (const float*)d_in[0];
    const float* wq = (const float*)d_in[1];
    const float* bq = (const float*)d_in[2];
    const float* wk = (const float*)d_in[3];
    const float* bk = (const float*)d_in[4];
    const float* wv = (const float*)d_in[5];
    const float* bv = (const float*)d_in[6];
    const float* w  = (const float*)d_in[7];
    const float* wo = (const float*)d_in[8];
    const float* bo = (const float*)d_in[9];

    // workspace layout (~193 MiB)
    char* p = (char*)d_ws;
    u16* expw = (u16*)p; p += (size_t)TT * TT * 2;        // 32 MiB
    u16* xbf  = (u16*)p; p += (size_t)BT * FF * 2;        // 16 MiB (reused as Yt)
    u16* wqb  = (u16*)p; p += (size_t)FF * FF * 2;
    u16* wkb  = (u16*)p; p += (size_t)FF * FF * 2;
    u16* wvb  = (u16*)p; p += (size_t)FF * FF * 2;
    u16* wob  = (u16*)p; p += (size_t)FF * FF * 2;
    u16* qsig = (u16*)p; p += (size_t)BT * FF * 2;        // 16 MiB
    u16* kraw = (u16*)p; p += (size_t)BT * FF * 2;        // 16 MiB
    u16* vraw = (u16*)p; p += (size_t)BT * FF * 2;        // 16 MiB
    u16* mt   = (u16*)p; p += (size_t)BB * 512 * TT * 2;  // 32 MiB
    float* G  = (float*)p; p += (size_t)BT * 512 * 4;     // 64 MiB
    u16* yt = xbf;  // x dead after projections

    // 1. exp_w
    expw_kernel<<<TT, 256, 0, stream>>>(w, expw);

    // 2. casts
    cvt_bf16_kernel<<<(BT * FF / 4 + 255) / 256, 256, 0, stream>>>(x, xbf, BT * FF / 4);
    cvt_bf16_kernel<<<(FF * FF / 4 + 255) / 256, 256, 0, stream>>>(wq, wqb, FF * FF / 4);
    cvt_bf16_kernel<<<(FF * FF / 4 + 255) / 256, 256, 0, stream>>>(wk, wkb, FF * FF / 4);
    cvt_bf16_kernel<<<(FF * FF / 4 + 255) / 256, 256, 0, stream>>>(wv, wvb, FF * FF / 4);
    cvt_bf16_kernel<<<(FF * FF / 4 + 255) / 256, 256, 0, stream>>>(wo, wob, FF * FF / 4);

    // 3. projections
    dim3 gp(BT / 128, FF / 128, 1);
    gemm_nt<1><<<gp, 256, 0, stream>>>(xbf, wqb, bq, qsig, BT, FF, FF, 0, 0, 0);
    gemm_nt<2><<<gp, 256, 0, stream>>>(xbf, wkb, bk, kraw, BT, FF, FF, 0, 0, 0);
    gemm_nt<2><<<gp, 256, 0, stream>>>(xbf, wvb, bv, vraw, BT, FF, FF, 0, 0, 0);

    // 4. Mt build
    build_mt<<<dim3(TT / 64, BB), 256, 0, stream>>>(kraw, vraw, mt);

    // 5. big batched GEMM: G[b] = exp_w @ Mt[b]^T   (A stride 0)
    gemm_nt<0><<<dim3(TT / 128, 512 / 128, BB), 256, 0, stream>>>(
        expw, mt, nullptr, G, TT, 512, TT, 0, (long long)512 * TT, (long long)TT * 512);

    // 6. Yt epilogue
    epilogue_kernel<<<2048, 256, 0, stream>>>(qsig, G, yt);

    // 7. output projection -> d_out (f32)
    gemm_nt<0><<<gp, 256, 0, stream>>>(yt, wob, bo, (float*)d_out, BT, FF, FF, 0, 0, 0);
}

// Round 2
// 333.117 us; speedup vs baseline: 1.0255x; 1.0255x over previous
//
#include <hip/hip_runtime.h>
#include <hip/hip_bf16.h>

// Problem constants
#define BB 8
#define TT 4096
#define FF 256
#define BT 32768   // BB*TT

typedef unsigned short u16;
typedef __attribute__((ext_vector_type(8))) short short8;
typedef __attribute__((ext_vector_type(4))) float f32x4;
typedef __attribute__((ext_vector_type(4))) unsigned int u32x4;

static __device__ __forceinline__ float bf2f(u16 u) {
    union { unsigned int i; float f; } v; v.i = ((unsigned int)u) << 16; return v.f;
}
static __device__ __forceinline__ u16 f2bf(float f) {
    union { float f; unsigned int i; } v; v.f = f;
    unsigned int x = v.i;
    return (u16)((x + 0x7fffu + ((x >> 16) & 1u)) >> 16);  // RNE
}

// ---------------------------------------------------------------------------
// exp_w: per-row max then exp(w - max) -> bf16 [T][T]
// ---------------------------------------------------------------------------
__global__ __launch_bounds__(256) void expw_kernel(const float* __restrict__ w,
                                                   u16* __restrict__ ew) {
    __shared__ float red[256];
    int row = blockIdx.x;
    int tid = threadIdx.x;
    const float* wr = w + (size_t)row * TT;

    f32x4 vals[4];
    float m = -1e30f;
#pragma unroll
    for (int v = 0; v < 4; ++v) {
        int idx = (v * 256 + tid) * 4;
        vals[v] = *(const f32x4*)(wr + idx);
#pragma unroll
        for (int j = 0; j < 4; ++j) m = fmaxf(m, vals[v][j]);
    }
    red[tid] = m;
    __syncthreads();
    for (int s = 128; s > 0; s >>= 1) {
        if (tid < s) red[tid] = fmaxf(red[tid], red[tid + s]);
        __syncthreads();
    }
    float rm = red[0];
#pragma unroll
    for (int v = 0; v < 4; ++v) {
        int idx = (v * 256 + tid) * 4;
        float e0 = expf(vals[v][0] - rm), e1 = expf(vals[v][1] - rm);
        float e2 = expf(vals[v][2] - rm), e3 = expf(vals[v][3] - rm);
        uint2 pk;
        pk.x = (unsigned int)f2bf(e0) | ((unsigned int)f2bf(e1) << 16);
        pk.y = (unsigned int)f2bf(e2) | ((unsigned int)f2bf(e3) << 16);
        *(uint2*)(ew + (size_t)row * TT + idx) = pk;
    }
}

// ---------------------------------------------------------------------------
// generic f32 -> bf16 cast, 4 elems/thread
// ---------------------------------------------------------------------------
__global__ __launch_bounds__(256) void cvt_bf16_kernel(const float* __restrict__ in,
                                                       u16* __restrict__ out, int n4) {
    int i = blockIdx.x * 256 + threadIdx.x;
    if (i < n4) {
        f32x4 v = ((const f32x4*)in)[i];
        uint2 pk;
        pk.x = (unsigned int)f2bf(v[0]) | ((unsigned int)f2bf(v[1]) << 16);
        pk.y = (unsigned int)f2bf(v[2]) | ((unsigned int)f2bf(v[3]) << 16);
        ((uint2*)out)[i] = pk;
    }
}

// ---------------------------------------------------------------------------
// NT GEMM: C[M,N] = A[M,K] * B[N,K]^T (+bias over N), bf16 in, f32 acc.
// 128x128 tile, BK=32, 4 waves (2x2), each wave 64x64 via 4x4 of 16x16x32 MFMA.
// Staging: global_load_lds dwordx4, linear LDS (m97 structure).
// MODE 0: f32 out (+bias if non-null); 1: sigmoid -> bf16; 2: (+bias) -> bf16
// ---------------------------------------------------------------------------
typedef const __attribute__((address_space(1))) void gvoid_t;
typedef __attribute__((address_space(3))) void svoid_t;

template <int MODE>
__global__ __launch_bounds__(256) void gemm_nt(const u16* __restrict__ Aall,
                                               const u16* __restrict__ Ball,
                                               const float* __restrict__ bias,
                                               void* __restrict__ Call,
                                               int M, int N, int K,
                                               long long strideA, long long strideB,
                                               long long strideC) {
    __shared__ u16 As[128 * 32];   // linear: row stride 32 elems (64 B)
    __shared__ u16 Bs[128 * 32];

    const u16* A = Aall + (size_t)blockIdx.z * strideA;
    const u16* Bm = Ball + (size_t)blockIdx.z * strideB;

    int tid = threadIdx.x;
    int lane = tid & 63;
    int w = tid >> 6;
    int wr = w >> 1, wc = w & 1;
    int fr = lane & 15, kg = lane >> 4;

    f32x4 acc[4][4];
#pragma unroll
    for (int m = 0; m < 4; ++m)
#pragma unroll
        for (int n = 0; n < 4; ++n) acc[m][n] = (f32x4){0.f, 0.f, 0.f, 0.f};

    int bm = blockIdx.x, bn = blockIdx.y;
    int nk = K >> 5;

    // staging geometry: each thread owns one 16B chunk: row = tid>>2 (+64 for
    // 2nd issue), chunk = tid&3. LDS dest = tid*16B (wave-uniform base+lane*16).
    int srow = tid >> 2;
    int schunk = (tid & 3) << 3;  // elem offset within row
    const u16* aBase = A + (size_t)(bm * 128 + srow) * K + schunk;
    const u16* bBase = Bm + (size_t)(bn * 128 + srow) * K + schunk;
    size_t half = (size_t)64 * K;   // 64 rows down

    for (int kt = 0; kt < nk; ++kt) {
        __syncthreads();   // previous-iter LDS reads done before overwrite
        int ko = kt << 5;
        __builtin_amdgcn_global_load_lds((gvoid_t*)(aBase + ko), (svoid_t*)&As[tid * 8], 16, 0, 0);
        __builtin_amdgcn_global_load_lds((gvoid_t*)(aBase + half + ko), (svoid_t*)&As[2048 + tid * 8], 16, 0, 0);
        __builtin_amdgcn_global_load_lds((gvoid_t*)(bBase + ko), (svoid_t*)&Bs[tid * 8], 16, 0, 0);
        __builtin_amdgcn_global_load_lds((gvoid_t*)(bBase + half + ko), (svoid_t*)&Bs[2048 + tid * 8], 16, 0, 0);
        __syncthreads();   // compiler drains vmcnt before barrier

        short8 af[4], bfr[4];
#pragma unroll
        for (int m = 0; m < 4; ++m)
            af[m] = *(const short8*)&As[(wr * 64 + m * 16 + fr) * 32 + kg * 8];
#pragma unroll
        for (int n = 0; n < 4; ++n)
            bfr[n] = *(const short8*)&Bs[(wc * 64 + n * 16 + fr) * 32 + kg * 8];
#pragma unroll
        for (int m = 0; m < 4; ++m)
#pragma unroll
            for (int n = 0; n < 4; ++n)
                acc[m][n] = __builtin_amdgcn_mfma_f32_16x16x32_bf16(af[m], bfr[n], acc[m][n], 0, 0, 0);
    }

    int row0 = bm * 128 + wr * 64;
    int col0 = bn * 128 + wc * 64;
    size_t cbase = (size_t)blockIdx.z * strideC;
#pragma unroll
    for (int n = 0; n < 4; ++n) {
        int col = col0 + n * 16 + fr;
        float bv = bias ? bias[col] : 0.0f;
#pragma unroll
        for (int m = 0; m < 4; ++m) {
            int rbase = row0 + m * 16 + kg * 4;
#pragma unroll
            for (int i = 0; i < 4; ++i) {
                float val = acc[m][n][i] + bv;
                size_t idx = cbase + (size_t)(rbase + i) * N + col;
                if (MODE == 0)
                    ((float*)Call)[idx] = val;
                else if (MODE == 1)
                    ((u16*)Call)[idx] = f2bf(1.0f / (1.0f + expf(-val)));
                else
                    ((u16*)Call)[idx] = f2bf(val);
            }
        }
    }
}

// ---------------------------------------------------------------------------
// Build Mt[b][512][T]: row 2f = expK*V feature f, row 2f+1 = expK feature f
// (exp over feature-dim max per (b,s) row). 64 s-rows per block.
// ---------------------------------------------------------------------------
__global__ __launch_bounds__(256) void build_mt(const u16* __restrict__ Kraw,
                                                const u16* __restrict__ Vraw,
                                                u16* __restrict__ Mt) {
    __shared__ u16 Ks[64][264];
    __shared__ u16 Vs[64][264];
    __shared__ float part[64][4];
    __shared__ float rmax[64];

    int s0 = blockIdx.x * 64;
    int b = blockIdx.y;
    int tid = threadIdx.x;
    size_t base = ((size_t)b * TT + s0) * FF;

#pragma unroll
    for (int v = 0; v < 8; ++v) {
        int i = v * 256 + tid;       // 0..2047 vectors of 8
        int row = i >> 5;
        int cb = (i & 31) << 3;
        *(u32x4*)&Ks[row][cb] = *(const u32x4*)(Kraw + base + (size_t)row * FF + cb);
        *(u32x4*)&Vs[row][cb] = *(const u32x4*)(Vraw + base + (size_t)row * FF + cb);
    }
    __syncthreads();
    {
        int row = tid >> 2, p = tid & 3;
        float m = -1e30f;
        for (int c = p * 64; c < p * 64 + 64; ++c) m = fmaxf(m, bf2f(Ks[row][c]));
        part[row][p] = m;
    }
    __syncthreads();
    if (tid < 64)
        rmax[tid] = fmaxf(fmaxf(part[tid][0], part[tid][1]), fmaxf(part[tid][2], part[tid][3]));
    __syncthreads();

    int f = tid >> 5;
    int lane = tid & 31;
    int sl = lane << 1;
    size_t mtb = (size_t)b * 512 * TT;
    for (int fb = 0; fb < 256; fb += 8) {
        int fi = fb + f;
        float ek0 = expf(bf2f(Ks[sl][fi]) - rmax[sl]);
        float ek1 = expf(bf2f(Ks[sl + 1][fi]) - rmax[sl + 1]);
        float nm0 = ek0 * bf2f(Vs[sl][fi]);
        float nm1 = ek1 * bf2f(Vs[sl + 1][fi]);
        unsigned int pn = (unsigned int)f2bf(nm0) | ((unsigned int)f2bf(nm1) << 16);
        unsigned int pd = (unsigned int)f2bf(ek0) | ((unsigned int)f2bf(ek1) << 16);
        *(unsigned int*)(Mt + mtb + (size_t)(2 * fi) * TT + s0 + sl) = pn;
        *(unsigned int*)(Mt + mtb + (size_t)(2 * fi + 1) * TT + s0 + sl) = pd;
    }
}

// ---------------------------------------------------------------------------
// Yt = sigmoid(Q) * num/den  (Qsig already sigmoided, bf16)
// G layout: [BT][512] f32, cols 2f = num, 2f+1 = den
// ---------------------------------------------------------------------------
__global__ __launch_bounds__(256) void epilogue_kernel(const u16* __restrict__ Qsig,
                                                       const float* __restrict__ G,
                                                       u16* __restrict__ Yt) {
    size_t total = (size_t)BT * FF;
    for (size_t i = (size_t)blockIdx.x * 256 + threadIdx.x; i < total;
         i += (size_t)gridDim.x * 256) {
        size_t r = i >> 8;
        int f = (int)(i & 255);
        float2 g = *(const float2*)(G + r * 512 + 2 * f);
        float q = bf2f(Qsig[i]);
        Yt[i] = f2bf(q * g.x / g.y);
    }
}

// ---------------------------------------------------------------------------
extern "C" void kernel_launch(void* const* d_in, const int* in_sizes, int n_in,
                              void* d_out, int out_size, void* d_ws, size_t ws_size,
                              hipStream_t stream) {
    const float* x  = (const float*)d_in[0];
    const float* wq = (const float*)d_in[1];
    const float* bq = (const float*)d_in[2];
    const float* wk = (const float*)d_in[3];
    const float* bk = (const float*)d_in[4];
    const float* wv = (const float*)d_in[5];
    const float* bv = (const float*)d_in[6];
    const float* w  = (const float*)d_in[7];
    const float* wo = (const float*)d_in[8];
    const float* bo = (const float*)d_in[9];

    // workspace layout (~193 MiB)
    char* p = (char*)d_ws;
    u16* expw = (u16*)p; p += (size_t)TT * TT * 2;        // 32 MiB
    u16* xbf  = (u16*)p; p += (size_t)BT * FF * 2;        // 16 MiB (reused as Yt)
    u16* wqb  = (u16*)p; p += (size_t)FF * FF * 2;
    u16* wkb  = (u16*)p; p += (size_t)FF * FF * 2;
    u16* wvb  = (u16*)p; p += (size_t)FF * FF * 2;
    u16* wob  = (u16*)p; p += (size_t)FF * FF * 2;
    u16* qsig = (u16*)p; p += (size_t)BT * FF * 2;        // 16 MiB
    u16* kraw = (u16*)p; p += (size_t)BT * FF * 2;        // 16 MiB
    u16* vraw = (u16*)p; p += (size_t)BT * FF * 2;        // 16 MiB
    u16* mt   = (u16*)p; p += (size_t)BB * 512 * TT * 2;  // 32 MiB
    float* G  = (float*)p; p += (size_t)BT * 512 * 4;     // 64 MiB
    u16* yt = xbf;  // x dead after projections

    // 1. exp_w
    expw_kernel<<<TT, 256, 0, stream>>>(w, expw);

    // 2. casts
    cvt_bf16_kernel<<<(BT * FF / 4 + 255) / 256, 256, 0, stream>>>(x, xbf, BT * FF / 4);
    cvt_bf16_kernel<<<(FF * FF / 4 + 255) / 256, 256, 0, stream>>>(wq, wqb, FF * FF / 4);
    cvt_bf16_kernel<<<(FF * FF / 4 + 255) / 256, 256, 0, stream>>>(wk, wkb, FF * FF / 4);
    cvt_bf16_kernel<<<(FF * FF / 4 + 255) / 256, 256, 0, stream>>>(wv, wvb, FF * FF / 4);
    cvt_bf16_kernel<<<(FF * FF / 4 + 255) / 256, 256, 0, stream>>>(wo, wob, FF * FF / 4);

    // 3. projections
    dim3 gp(BT / 128, FF / 128, 1);
    gemm_nt<1><<<gp, 256, 0, stream>>>(xbf, wqb, bq, qsig, BT, FF, FF, 0, 0, 0);
    gemm_nt<2><<<gp, 256, 0, stream>>>(xbf, wkb, bk, kraw, BT, FF, FF, 0, 0, 0);
    gemm_nt<2><<<gp, 256, 0, stream>>>(xbf, wvb, bv, vraw, BT, FF, FF, 0, 0, 0);

    // 4. Mt build
    build_mt<<<dim3(TT / 64, BB), 256, 0, stream>>>(kraw, vraw, mt);

    // 5. big batched GEMM: G[b] = exp_w @ Mt[b]^T   (A stride 0)
    gemm_nt<0><<<dim3(TT / 128, 512 / 128, BB), 256, 0, stream>>>(
        expw, mt, nullptr, G, TT, 512, TT, 0, (long long)512 * TT, (long long)TT * 512);

    // 6. Yt epilogue
    epilogue_kernel<<<2048, 256, 0, stream>>>(qsig, G, yt);

    // 7. output projection -> d_out (f32)
    gemm_nt<0><<<gp, 256, 0, stream>>>(yt, wob, bo, (float*)d_out, BT, FF, FF, 0, 0, 0);
}

// Round 3
// 241.602 us; speedup vs baseline: 1.4140x; 1.3788x over previous
//
#include <hip/hip_runtime.h>
#include <hip/hip_bf16.h>

// Problem constants
#define BB 8
#define TT 4096
#define FF 256
#define BT 32768   // BB*TT

typedef unsigned short u16;
typedef __attribute__((ext_vector_type(8))) short short8;
typedef __attribute__((ext_vector_type(4))) float f32x4;
typedef __attribute__((ext_vector_type(4))) unsigned int u32x4;

static __device__ __forceinline__ float bf2f(u16 u) {
    union { unsigned int i; float f; } v; v.i = ((unsigned int)u) << 16; return v.f;
}
static __device__ __forceinline__ u16 f2bf(float f) {
    union { float f; unsigned int i; } v; v.f = f;
    unsigned int x = v.i;
    return (u16)((x + 0x7fffu + ((x >> 16) & 1u)) >> 16);  // RNE
}

typedef const __attribute__((address_space(1))) void gvoid_t;
typedef __attribute__((address_space(3))) void svoid_t;

// ---------------------------------------------------------------------------
// exp_w: per-row max then exp(w - max) -> bf16 [T][T]
// ---------------------------------------------------------------------------
__global__ __launch_bounds__(256) void expw_kernel(const float* __restrict__ w,
                                                   u16* __restrict__ ew) {
    __shared__ float red[256];
    int row = blockIdx.x;
    int tid = threadIdx.x;
    const float* wr = w + (size_t)row * TT;

    f32x4 vals[4];
    float m = -1e30f;
#pragma unroll
    for (int v = 0; v < 4; ++v) {
        int idx = (v * 256 + tid) * 4;
        vals[v] = *(const f32x4*)(wr + idx);
#pragma unroll
        for (int j = 0; j < 4; ++j) m = fmaxf(m, vals[v][j]);
    }
    red[tid] = m;
    __syncthreads();
    for (int s = 128; s > 0; s >>= 1) {
        if (tid < s) red[tid] = fmaxf(red[tid], red[tid + s]);
        __syncthreads();
    }
    float rm = red[0];
#pragma unroll
    for (int v = 0; v < 4; ++v) {
        int idx = (v * 256 + tid) * 4;
        float e0 = expf(vals[v][0] - rm), e1 = expf(vals[v][1] - rm);
        float e2 = expf(vals[v][2] - rm), e3 = expf(vals[v][3] - rm);
        uint2 pk;
        pk.x = (unsigned int)f2bf(e0) | ((unsigned int)f2bf(e1) << 16);
        pk.y = (unsigned int)f2bf(e2) | ((unsigned int)f2bf(e3) << 16);
        *(uint2*)(ew + (size_t)row * TT + idx) = pk;
    }
}

// ---------------------------------------------------------------------------
// generic f32 -> bf16 cast, 4 elems/thread
// ---------------------------------------------------------------------------
__global__ __launch_bounds__(256) void cvt_bf16_kernel(const float* __restrict__ in,
                                                       u16* __restrict__ out, int n4) {
    int i = blockIdx.x * 256 + threadIdx.x;
    if (i < n4) {
        f32x4 v = ((const f32x4*)in)[i];
        uint2 pk;
        pk.x = (unsigned int)f2bf(v[0]) | ((unsigned int)f2bf(v[1]) << 16);
        pk.y = (unsigned int)f2bf(v[2]) | ((unsigned int)f2bf(v[3]) << 16);
        ((uint2*)out)[i] = pk;
    }
}

// ---------------------------------------------------------------------------
// Small NT GEMM (m97 structure) for the 4 projection GEMMs.
// C[M,N] = A[M,K]*B[N,K]^T (+bias). MODE 0: f32 out; 1: sigmoid->bf16; 2: ->bf16
// ---------------------------------------------------------------------------
template <int MODE>
__global__ __launch_bounds__(256) void gemm_nt(const u16* __restrict__ A,
                                               const u16* __restrict__ Bm,
                                               const float* __restrict__ bias,
                                               void* __restrict__ Call,
                                               int M, int N, int K) {
    __shared__ u16 As[128 * 32];
    __shared__ u16 Bs[128 * 32];

    int tid = threadIdx.x;
    int lane = tid & 63;
    int w = tid >> 6;
    int wr = w >> 1, wc = w & 1;
    int fr = lane & 15, kg = lane >> 4;

    f32x4 acc[4][4];
#pragma unroll
    for (int m = 0; m < 4; ++m)
#pragma unroll
        for (int n = 0; n < 4; ++n) acc[m][n] = (f32x4){0.f, 0.f, 0.f, 0.f};

    int bm = blockIdx.x, bn = blockIdx.y;
    int nk = K >> 5;

    int srow = tid >> 2;
    int schunk = (tid & 3) << 3;
    const u16* aBase = A + (size_t)(bm * 128 + srow) * K + schunk;
    const u16* bBase = Bm + (size_t)(bn * 128 + srow) * K + schunk;
    size_t half = (size_t)64 * K;

    for (int kt = 0; kt < nk; ++kt) {
        __syncthreads();
        int ko = kt << 5;
        __builtin_amdgcn_global_load_lds((gvoid_t*)(aBase + ko), (svoid_t*)&As[tid * 8], 16, 0, 0);
        __builtin_amdgcn_global_load_lds((gvoid_t*)(aBase + half + ko), (svoid_t*)&As[2048 + tid * 8], 16, 0, 0);
        __builtin_amdgcn_global_load_lds((gvoid_t*)(bBase + ko), (svoid_t*)&Bs[tid * 8], 16, 0, 0);
        __builtin_amdgcn_global_load_lds((gvoid_t*)(bBase + half + ko), (svoid_t*)&Bs[2048 + tid * 8], 16, 0, 0);
        __syncthreads();

        short8 af[4], bfr[4];
#pragma unroll
        for (int m = 0; m < 4; ++m)
            af[m] = *(const short8*)&As[(wr * 64 + m * 16 + fr) * 32 + kg * 8];
#pragma unroll
        for (int n = 0; n < 4; ++n)
            bfr[n] = *(const short8*)&Bs[(wc * 64 + n * 16 + fr) * 32 + kg * 8];
#pragma unroll
        for (int m = 0; m < 4; ++m)
#pragma unroll
            for (int n = 0; n < 4; ++n)
                acc[m][n] = __builtin_amdgcn_mfma_f32_16x16x32_bf16(af[m], bfr[n], acc[m][n], 0, 0, 0);
    }

    int row0 = bm * 128 + wr * 64;
    int col0 = bn * 128 + wc * 64;
#pragma unroll
    for (int n = 0; n < 4; ++n) {
        int col = col0 + n * 16 + fr;
        float bv = bias ? bias[col] : 0.0f;
#pragma unroll
        for (int m = 0; m < 4; ++m) {
            int rbase = row0 + m * 16 + kg * 4;
#pragma unroll
            for (int i = 0; i < 4; ++i) {
                float val = acc[m][n][i] + bv;
                size_t idx = (size_t)(rbase + i) * N + col;
                if (MODE == 0)
                    ((float*)Call)[idx] = val;
                else if (MODE == 1)
                    ((u16*)Call)[idx] = f2bf(1.0f / (1.0f + expf(-val)));
                else
                    ((u16*)Call)[idx] = f2bf(val);
            }
        }
    }
}

// ---------------------------------------------------------------------------
// Big 4096^3 NT GEMM, phase-pipelined (T2+T3+T4+T5).
// BM=BN=256, BK=32, 8 waves (2Mx4N), each wave 128x64 via 8x4 16x16x32 MFMA.
// 4 LDS K-tile buffers (128 KiB): tile t reads buf[t&3], stages buf[(t+2)&3].
// One counted vmcnt(4) per tile (never 0). XOR-swizzled LDS:
//   logical (row, cbyte<64): prow=row>>1, phys = prow*128 + (((row&1)<<6|cbyte)
//   ^ ((prow&7)<<4)). Staging keeps gload_lds dest linear; the SOURCE global
//   address is inverse-swizzled (rule 21 / m173). Reads: 16 lanes -> 16
//   distinct 16B slots -> all 32 banks, 2-way (free).
// ---------------------------------------------------------------------------
#define GLDS(src, eoff) \
    __builtin_amdgcn_global_load_lds((gvoid_t*)(src), (svoid_t*)&L[eoff], 16, 0, 0)

__global__ __launch_bounds__(512, 2) void gemm256_nt(const u16* __restrict__ A,
                                                     const u16* __restrict__ B,
                                                     float* __restrict__ C) {
    __shared__ u16 L[65536];   // 128 KiB: A bufs [0,32768) elems, B bufs [32768,65536)
    const int K = 4096, nt = 128;
    int tid = threadIdx.x;
    int lane = tid & 63, wid = tid >> 6;
    int fr = lane & 15, kg = lane >> 4;
    int wr = wid >> 2, wc = wid & 3;
    int bm = blockIdx.x, bn = blockIdx.y;

    // ds_read base byte offsets within a 16KB buf region (swizzled)
    int xpart = (((fr & 1) << 6) | (kg << 4)) ^ (((fr >> 1) & 7) << 4);
    int aoff = (wr * 64 + (fr >> 1)) * 128 + xpart;
    int boff = (wc * 32 + (fr >> 1)) * 128 + xpart;

    // staging: thread fills phys bytes wid*2048 + lane*16 (+1024). Inverse-swizzle
    // gives its global source element.
    int l8 = lane >> 3;
    int v = (lane & 7) ^ l8;
    int srow = wid * 32 + l8 * 2 + (v >> 2);
    int scol = (v & 3) * 8;
    const u16* sA = A + (size_t)(bm * 256 + srow) * K + scol;
    const u16* sB = B + (size_t)(bn * 256 + srow) * K + scol;
    int dA = (wid * 2048) / 2 + lane * 8;    // elem offset, buf 0, A region
    int dB = dA + 32768;                     // B region

    f32x4 acc[8][4];
#pragma unroll
    for (int m = 0; m < 8; ++m)
#pragma unroll
        for (int n = 0; n < 4; ++n) acc[m][n] = (f32x4){0.f, 0.f, 0.f, 0.f};

    // prologue: stage tiles 0 and 1 (per-wave order A,A,B,B per tile)
#pragma unroll
    for (int tt = 0; tt < 2; ++tt) {
        const u16* a = sA + tt * 32;
        const u16* b = sB + tt * 32;
        int qe = tt * 8192;
        GLDS(a, dA + qe);
        GLDS(a + 16 * K, dA + qe + 512);
        GLDS(b, dB + qe);
        GLDS(b + 16 * K, dB + qe + 512);
    }
    asm volatile("s_waitcnt vmcnt(4)" ::: "memory");
    __builtin_amdgcn_sched_barrier(0);
    __builtin_amdgcn_s_barrier();

    const char* LB = (const char*)L;
#pragma unroll 1
    for (int t = 0; t < nt; ++t) {
        int p = t & 3;
        int q = (t + 2) & 3;
        int ks = (t + 2 < nt) ? t + 2 : 0;
        int abase = p * 16384 + aoff;
        int bbase = 65536 + p * 16384 + boff;

        // ---- phase 1: all ds_reads, stage A(t+2), MFMA n0-1 ----
        short8 af[8], bf4[4];
#pragma unroll
        for (int m = 0; m < 8; ++m) af[m] = *(const short8*)(LB + abase + m * 1024);
#pragma unroll
        for (int n = 0; n < 4; ++n) bf4[n] = *(const short8*)(LB + bbase + n * 1024);
        const u16* a = sA + ks * 32;
        GLDS(a, dA + q * 8192);
        GLDS(a + 16 * K, dA + q * 8192 + 512);
        asm volatile("s_waitcnt lgkmcnt(0)" ::: "memory");
        __builtin_amdgcn_sched_barrier(0);
        __builtin_amdgcn_s_setprio(1);
#pragma unroll
        for (int m = 0; m < 8; ++m)
#pragma unroll
            for (int n = 0; n < 2; ++n)
                acc[m][n] = __builtin_amdgcn_mfma_f32_16x16x32_bf16(af[m], bf4[n], acc[m][n], 0, 0, 0);
        __builtin_amdgcn_s_setprio(0);
        __builtin_amdgcn_s_barrier();

        // ---- phase 2: stage B(t+2), MFMA n2-3, counted vmcnt ----
        const u16* b = sB + ks * 32;
        GLDS(b, dB + q * 8192);
        GLDS(b + 16 * K, dB + q * 8192 + 512);
        __builtin_amdgcn_s_setprio(1);
#pragma unroll
        for (int m = 0; m < 8; ++m)
#pragma unroll
            for (int n = 2; n < 4; ++n)
                acc[m][n] = __builtin_amdgcn_mfma_f32_16x16x32_bf16(af[m], bf4[n], acc[m][n], 0, 0, 0);
        __builtin_amdgcn_s_setprio(0);
        asm volatile("s_waitcnt vmcnt(4)" ::: "memory");   // t+1 fully landed; t+2 in flight
        __builtin_amdgcn_sched_barrier(0);
        __builtin_amdgcn_s_barrier();
    }

    // epilogue: C[4096][4096] f32
    int row0 = bm * 256 + wr * 128;
    int col0 = bn * 256 + wc * 64;
#pragma unroll
    for (int n = 0; n < 4; ++n) {
        int col = col0 + n * 16 + fr;
#pragma unroll
        for (int m = 0; m < 8; ++m) {
            int r = row0 + m * 16 + kg * 4;
#pragma unroll
            for (int i = 0; i < 4; ++i)
                C[(size_t)(r + i) * 4096 + col] = acc[m][n][i];
        }
    }
}

// ---------------------------------------------------------------------------
// Build Mt flat [4096][T]: row b*512+2f = expK*V feature f, b*512+2f+1 = expK
// (exp over feature-dim max per (b,s) row). 64 s-rows per block.
// ---------------------------------------------------------------------------
__global__ __launch_bounds__(256) void build_mt(const u16* __restrict__ Kraw,
                                                const u16* __restrict__ Vraw,
                                                u16* __restrict__ Mt) {
    __shared__ u16 Ks[64][264];
    __shared__ u16 Vs[64][264];
    __shared__ float part[64][4];
    __shared__ float rmax[64];

    int s0 = blockIdx.x * 64;
    int b = blockIdx.y;
    int tid = threadIdx.x;
    size_t base = ((size_t)b * TT + s0) * FF;

#pragma unroll
    for (int v = 0; v < 8; ++v) {
        int i = v * 256 + tid;
        int row = i >> 5;
        int cb = (i & 31) << 3;
        *(u32x4*)&Ks[row][cb] = *(const u32x4*)(Kraw + base + (size_t)row * FF + cb);
        *(u32x4*)&Vs[row][cb] = *(const u32x4*)(Vraw + base + (size_t)row * FF + cb);
    }
    __syncthreads();
    {
        int row = tid >> 2, p = tid & 3;
        float m = -1e30f;
        for (int c = p * 64; c < p * 64 + 64; ++c) m = fmaxf(m, bf2f(Ks[row][c]));
        part[row][p] = m;
    }
    __syncthreads();
    if (tid < 64)
        rmax[tid] = fmaxf(fmaxf(part[tid][0], part[tid][1]), fmaxf(part[tid][2], part[tid][3]));
    __syncthreads();

    int f = tid >> 5;
    int lane = tid & 31;
    int sl = lane << 1;
    size_t mtb = (size_t)b * 512 * TT;
    for (int fb = 0; fb < 256; fb += 8) {
        int fi = fb + f;
        float ek0 = expf(bf2f(Ks[sl][fi]) - rmax[sl]);
        float ek1 = expf(bf2f(Ks[sl + 1][fi]) - rmax[sl + 1]);
        float nm0 = ek0 * bf2f(Vs[sl][fi]);
        float nm1 = ek1 * bf2f(Vs[sl + 1][fi]);
        unsigned int pn = (unsigned int)f2bf(nm0) | ((unsigned int)f2bf(nm1) << 16);
        unsigned int pd = (unsigned int)f2bf(ek0) | ((unsigned int)f2bf(ek1) << 16);
        *(unsigned int*)(Mt + mtb + (size_t)(2 * fi) * TT + s0 + sl) = pn;
        *(unsigned int*)(Mt + mtb + (size_t)(2 * fi + 1) * TT + s0 + sl) = pd;
    }
}

// ---------------------------------------------------------------------------
// Yt = sigmoid(Q) * num/den. G layout: [T][4096] f32, col b*512+2f = num,
// b*512+2f+1 = den.
// ---------------------------------------------------------------------------
__global__ __launch_bounds__(256) void epilogue_kernel(const u16* __restrict__ Qsig,
                                                       const float* __restrict__ G,
                                                       u16* __restrict__ Yt) {
    size_t total = (size_t)BT * FF;
    for (size_t i = (size_t)blockIdx.x * 256 + threadIdx.x; i < total;
         i += (size_t)gridDim.x * 256) {
        size_t r = i >> 8;            // b*T + t
        int f = (int)(i & 255);
        int b = (int)(r >> 12);
        int tt = (int)(r & 4095);
        float2 g = *(const float2*)(G + (size_t)tt * 4096 + b * 512 + 2 * f);
        float q = bf2f(Qsig[i]);
        Yt[i] = f2bf(q * g.x / g.y);
    }
}

// ---------------------------------------------------------------------------
extern "C" void kernel_launch(void* const* d_in, const int* in_sizes, int n_in,
                              void* d_out, int out_size, void* d_ws, size_t ws_size,
                              hipStream_t stream) {
    const float* x  = (const float*)d_in[0];
    const float* wq = (const float*)d_in[1];
    const float* bq = (const float*)d_in[2];
    const float* wk = (const float*)d_in[3];
    const float* bk = (const float*)d_in[4];
    const float* wv = (const float*)d_in[5];
    const float* bv = (const float*)d_in[6];
    const float* w  = (const float*)d_in[7];
    const float* wo = (const float*)d_in[8];
    const float* bo = (const float*)d_in[9];

    char* p = (char*)d_ws;
    u16* expw = (u16*)p; p += (size_t)TT * TT * 2;        // 32 MiB
    u16* xbf  = (u16*)p; p += (size_t)BT * FF * 2;        // 16 MiB (reused as Yt)
    u16* wqb  = (u16*)p; p += (size_t)FF * FF * 2;
    u16* wkb  = (u16*)p; p += (size_t)FF * FF * 2;
    u16* wvb  = (u16*)p; p += (size_t)FF * FF * 2;
    u16* wob  = (u16*)p; p += (size_t)FF * FF * 2;
    u16* qsig = (u16*)p; p += (size_t)BT * FF * 2;        // 16 MiB
    u16* kraw = (u16*)p; p += (size_t)BT * FF * 2;        // 16 MiB
    u16* vraw = (u16*)p; p += (size_t)BT * FF * 2;        // 16 MiB
    u16* mt   = (u16*)p; p += (size_t)BB * 512 * TT * 2;  // 32 MiB (flat [4096][T])
    float* G  = (float*)p; p += (size_t)TT * 4096 * 4;    // 64 MiB ([T][4096])
    u16* yt = xbf;

    expw_kernel<<<TT, 256, 0, stream>>>(w, expw);

    cvt_bf16_kernel<<<(BT * FF / 4 + 255) / 256, 256, 0, stream>>>(x, xbf, BT * FF / 4);
    cvt_bf16_kernel<<<(FF * FF / 4 + 255) / 256, 256, 0, stream>>>(wq, wqb, FF * FF / 4);
    cvt_bf16_kernel<<<(FF * FF / 4 + 255) / 256, 256, 0, stream>>>(wk, wkb, FF * FF / 4);
    cvt_bf16_kernel<<<(FF * FF / 4 + 255) / 256, 256, 0, stream>>>(wv, wvb, FF * FF / 4);
    cvt_bf16_kernel<<<(FF * FF / 4 + 255) / 256, 256, 0, stream>>>(wo, wob, FF * FF / 4);

    dim3 gp(BT / 128, FF / 128, 1);
    gemm_nt<1><<<gp, 256, 0, stream>>>(xbf, wqb, bq, qsig, BT, FF, FF);
    gemm_nt<2><<<gp, 256, 0, stream>>>(xbf, wkb, bk, kraw, BT, FF, FF);
    gemm_nt<2><<<gp, 256, 0, stream>>>(xbf, wvb, bv, vraw, BT, FF, FF);

    build_mt<<<dim3(TT / 64, BB), 256, 0, stream>>>(kraw, vraw, mt);

    // flattened big GEMM: G[T][4096] = exp_w[T][T] @ MtFlat[4096][T]^T
    gemm256_nt<<<dim3(16, 16), 512, 0, stream>>>(expw, mt, G);

    epilogue_kernel<<<2048, 256, 0, stream>>>(qsig, G, yt);

    gemm_nt<0><<<gp, 256, 0, stream>>>(yt, wob, bo, (float*)d_out, BT, FF, FF);
}

// Round 4
// 229.688 us; speedup vs baseline: 1.4873x; 1.0519x over previous
//
#include <hip/hip_runtime.h>
#include <hip/hip_bf16.h>

// Problem constants
#define BB 8
#define TT 4096
#define FF 256
#define BT 32768   // BB*TT

typedef unsigned short u16;
typedef __attribute__((ext_vector_type(8))) short short8;
typedef __attribute__((ext_vector_type(4))) float f32x4;
typedef __attribute__((ext_vector_type(4))) unsigned int u32x4;

static __device__ __forceinline__ float bf2f(u16 u) {
    union { unsigned int i; float f; } v; v.i = ((unsigned int)u) << 16; return v.f;
}
static __device__ __forceinline__ u16 f2bf(float f) {
    union { float f; unsigned int i; } v; v.f = f;
    unsigned int x = v.i;
    return (u16)((x + 0x7fffu + ((x >> 16) & 1u)) >> 16);  // RNE
}

typedef const __attribute__((address_space(1))) void gvoid_t;
typedef __attribute__((address_space(3))) void svoid_t;

// ---------------------------------------------------------------------------
// exp_w: per-row max then exp(w - max) -> bf16 [T][T]
// ---------------------------------------------------------------------------
__global__ __launch_bounds__(256) void expw_kernel(const float* __restrict__ w,
                                                   u16* __restrict__ ew) {
    __shared__ float red[256];
    int row = blockIdx.x;
    int tid = threadIdx.x;
    const float* wr = w + (size_t)row * TT;

    f32x4 vals[4];
    float m = -1e30f;
#pragma unroll
    for (int v = 0; v < 4; ++v) {
        int idx = (v * 256 + tid) * 4;
        vals[v] = *(const f32x4*)(wr + idx);
#pragma unroll
        for (int j = 0; j < 4; ++j) m = fmaxf(m, vals[v][j]);
    }
    red[tid] = m;
    __syncthreads();
    for (int s = 128; s > 0; s >>= 1) {
        if (tid < s) red[tid] = fmaxf(red[tid], red[tid + s]);
        __syncthreads();
    }
    float rm = red[0];
#pragma unroll
    for (int v = 0; v < 4; ++v) {
        int idx = (v * 256 + tid) * 4;
        float e0 = expf(vals[v][0] - rm), e1 = expf(vals[v][1] - rm);
        float e2 = expf(vals[v][2] - rm), e3 = expf(vals[v][3] - rm);
        uint2 pk;
        pk.x = (unsigned int)f2bf(e0) | ((unsigned int)f2bf(e1) << 16);
        pk.y = (unsigned int)f2bf(e2) | ((unsigned int)f2bf(e3) << 16);
        *(uint2*)(ew + (size_t)row * TT + idx) = pk;
    }
}

// ---------------------------------------------------------------------------
// generic f32 -> bf16 cast, 4 elems/thread
// ---------------------------------------------------------------------------
__global__ __launch_bounds__(256) void cvt_bf16_kernel(const float* __restrict__ in,
                                                       u16* __restrict__ out, int n4) {
    int i = blockIdx.x * 256 + threadIdx.x;
    if (i < n4) {
        f32x4 v = ((const f32x4*)in)[i];
        uint2 pk;
        pk.x = (unsigned int)f2bf(v[0]) | ((unsigned int)f2bf(v[1]) << 16);
        pk.y = (unsigned int)f2bf(v[2]) | ((unsigned int)f2bf(v[3]) << 16);
        ((uint2*)out)[i] = pk;
    }
}

// ---------------------------------------------------------------------------
// Small NT GEMM (m97 structure) for the 4 projection GEMMs.
// C[M,N] = A[M,K]*B[N,K]^T (+bias). MODE 0: f32 out; 1: sigmoid->bf16; 2: ->bf16
// ---------------------------------------------------------------------------
template <int MODE>
__global__ __launch_bounds__(256) void gemm_nt(const u16* __restrict__ A,
                                               const u16* __restrict__ Bm,
                                               const float* __restrict__ bias,
                                               void* __restrict__ Call,
                                               int M, int N, int K) {
    __shared__ u16 As[128 * 32];
    __shared__ u16 Bs[128 * 32];

    int tid = threadIdx.x;
    int lane = tid & 63;
    int w = tid >> 6;
    int wr = w >> 1, wc = w & 1;
    int fr = lane & 15, kg = lane >> 4;

    f32x4 acc[4][4];
#pragma unroll
    for (int m = 0; m < 4; ++m)
#pragma unroll
        for (int n = 0; n < 4; ++n) acc[m][n] = (f32x4){0.f, 0.f, 0.f, 0.f};

    int bm = blockIdx.x, bn = blockIdx.y;
    int nk = K >> 5;

    int srow = tid >> 2;
    int schunk = (tid & 3) << 3;
    const u16* aBase = A + (size_t)(bm * 128 + srow) * K + schunk;
    const u16* bBase = Bm + (size_t)(bn * 128 + srow) * K + schunk;
    size_t half = (size_t)64 * K;

    for (int kt = 0; kt < nk; ++kt) {
        __syncthreads();
        int ko = kt << 5;
        __builtin_amdgcn_global_load_lds((gvoid_t*)(aBase + ko), (svoid_t*)&As[tid * 8], 16, 0, 0);
        __builtin_amdgcn_global_load_lds((gvoid_t*)(aBase + half + ko), (svoid_t*)&As[2048 + tid * 8], 16, 0, 0);
        __builtin_amdgcn_global_load_lds((gvoid_t*)(bBase + ko), (svoid_t*)&Bs[tid * 8], 16, 0, 0);
        __builtin_amdgcn_global_load_lds((gvoid_t*)(bBase + half + ko), (svoid_t*)&Bs[2048 + tid * 8], 16, 0, 0);
        __syncthreads();

        short8 af[4], bfr[4];
#pragma unroll
        for (int m = 0; m < 4; ++m)
            af[m] = *(const short8*)&As[(wr * 64 + m * 16 + fr) * 32 + kg * 8];
#pragma unroll
        for (int n = 0; n < 4; ++n)
            bfr[n] = *(const short8*)&Bs[(wc * 64 + n * 16 + fr) * 32 + kg * 8];
#pragma unroll
        for (int m = 0; m < 4; ++m)
#pragma unroll
            for (int n = 0; n < 4; ++n)
                acc[m][n] = __builtin_amdgcn_mfma_f32_16x16x32_bf16(af[m], bfr[n], acc[m][n], 0, 0, 0);
    }

    int row0 = bm * 128 + wr * 64;
    int col0 = bn * 128 + wc * 64;
#pragma unroll
    for (int n = 0; n < 4; ++n) {
        int col = col0 + n * 16 + fr;
        float bv = bias ? bias[col] : 0.0f;
#pragma unroll
        for (int m = 0; m < 4; ++m) {
            int rbase = row0 + m * 16 + kg * 4;
#pragma unroll
            for (int i = 0; i < 4; ++i) {
                float val = acc[m][n][i] + bv;
                size_t idx = (size_t)(rbase + i) * N + col;
                if (MODE == 0)
                    ((float*)Call)[idx] = val;
                else if (MODE == 1)
                    ((u16*)Call)[idx] = f2bf(1.0f / (1.0f + expf(-val)));
                else
                    ((u16*)Call)[idx] = f2bf(val);
            }
        }
    }
}

// ---------------------------------------------------------------------------
// Big 4096^3 NT GEMM, m201-style 4-phase/K-tile schedule, fused AFT epilogue.
// BM=BN=256, BK=64, 8 waves (2Mx4N), per-wave 128x64 = 8m x 4n 16x16x32 frags.
// LDS: A bufs 2x32KB [0,64KB), B bufs 2x32KB [64KB,128KB). Rows = 128B.
// Swizzle: phys_col_byte = logical_col_byte ^ ((row&7)<<4) (involution, both
// staging-source and ds_read use it; 2-way bank aliasing = free).
// Phases per tile t (buf p=t&1): P0 read A[m0-3]+B[n0-1] | stage B1(t+1);
// P1 read B[n2-3] | stage A1(t+1); P2 read A[m4-7] | stage B0(t+2);
// P3 no reads | stage A0(t+2), vmcnt(4).
// Liveness proof: B halves of tile t dead after t:P1 barrier, A halves after
// t:P2 -> every stage targets a dead half. vmcnt(4) at P3 leaves only the two
// t+2 halves in flight => all of t+1 landed before t+1:P0 reads.
// Epilogue: even-fr lanes hold num, odd hold den for the same f ->
// shfl_xor(1) + rcp, yt = sigmoid(Q)*num/den written bf16 directly.
// ---------------------------------------------------------------------------
#define GLDS(src, eoff) \
    __builtin_amdgcn_global_load_lds((gvoid_t*)(src), (svoid_t*)&L[eoff], 16, 0, 0)

#define STAGE_A(P_, H_, KS_) do {                                         \
    const u16* s_ = sA + (size_t)((H_) * 128) * 4096 + (KS_) * 64;        \
    GLDS(s_, (P_) * 16384 + (H_) * 8192 + tid * 8);                       \
    GLDS(s_ + (size_t)64 * 4096, (P_) * 16384 + (H_) * 8192 + 4096 + tid * 8); \
} while (0)

#define STAGE_B(P_, H_, KS_) do {                                         \
    const u16* s_ = sB + (size_t)((H_) * 128) * 4096 + (KS_) * 64;        \
    GLDS(s_, 32768 + (P_) * 16384 + (H_) * 8192 + tid * 8);               \
    GLDS(s_ + (size_t)64 * 4096, 32768 + (P_) * 16384 + (H_) * 8192 + 4096 + tid * 8); \
} while (0)

#define LOADA(FA, MB, AB) do {                                            \
    _Pragma("unroll")                                                     \
    for (int mi = 0; mi < 4; ++mi) {                                      \
        int rb_ = (AB) + (wr * 128 + ((MB) + mi) * 16 + fr) * 128;        \
        FA[mi][0] = *(const short8*)(LB + rb_ + colx0);                   \
        FA[mi][1] = *(const short8*)(LB + rb_ + colx1);                   \
    }                                                                     \
} while (0)

#define LOADB(FB, NB, BBB) do {                                           \
    _Pragma("unroll")                                                     \
    for (int ni = 0; ni < 2; ++ni) {                                      \
        int rb_ = (BBB) + (wc * 64 + ((NB) + ni) * 16 + fr) * 128;        \
        FB[ni][0] = *(const short8*)(LB + rb_ + colx0);                   \
        FB[ni][1] = *(const short8*)(LB + rb_ + colx1);                   \
    }                                                                     \
} while (0)

#define PH_OPEN() do {                                                    \
    __builtin_amdgcn_s_barrier();                                         \
    asm volatile("s_waitcnt lgkmcnt(0)" ::: "memory");                    \
    __builtin_amdgcn_sched_barrier(0);                                    \
} while (0)

#define MFMA_CLUSTER(FA, FB, M0, N0) do {                                 \
    __builtin_amdgcn_s_setprio(1);                                        \
    _Pragma("unroll")                                                     \
    for (int mi = 0; mi < 4; ++mi) {                                      \
        _Pragma("unroll")                                                 \
        for (int ni = 0; ni < 2; ++ni) {                                  \
            acc[(M0) + mi][(N0) + ni] = __builtin_amdgcn_mfma_f32_16x16x32_bf16( \
                FA[mi][0], FB[ni][0], acc[(M0) + mi][(N0) + ni], 0, 0, 0); \
            acc[(M0) + mi][(N0) + ni] = __builtin_amdgcn_mfma_f32_16x16x32_bf16( \
                FA[mi][1], FB[ni][1], acc[(M0) + mi][(N0) + ni], 0, 0, 0); \
        }                                                                 \
    }                                                                     \
    __builtin_amdgcn_s_setprio(0);                                        \
} while (0)

#define TILE(T_, P_) do {                                                 \
    const int Ab_ = (P_) * 32768;                                         \
    const int Bb_ = 65536 + (P_) * 32768;                                 \
    const int Pn_ = (P_) ^ 1;                                             \
    int ks1_ = ((T_) + 1 < 64) ? (T_) + 1 : 0;                            \
    int ks2_ = ((T_) + 2 < 64) ? (T_) + 2 : 0;                            \
    /* P0 */                                                              \
    LOADA(fa, 0, Ab_); LOADB(fb0, 0, Bb_);                                \
    STAGE_B(Pn_, 1, ks1_);                                                \
    PH_OPEN(); MFMA_CLUSTER(fa, fb0, 0, 0);                               \
    __builtin_amdgcn_s_barrier();                                         \
    /* P1 */                                                              \
    LOADB(fb1, 2, Bb_);                                                   \
    STAGE_A(Pn_, 1, ks1_);                                                \
    PH_OPEN(); MFMA_CLUSTER(fa, fb1, 0, 2);                               \
    __builtin_amdgcn_s_barrier();                                         \
    /* P2 */                                                              \
    LOADA(fa, 4, Ab_);                                                    \
    STAGE_B(P_, 0, ks2_);                                                 \
    PH_OPEN(); MFMA_CLUSTER(fa, fb0, 4, 0);                               \
    __builtin_amdgcn_s_barrier();                                         \
    /* P3 */                                                              \
    STAGE_A(P_, 0, ks2_);                                                 \
    __builtin_amdgcn_s_barrier();                                         \
    MFMA_CLUSTER(fa, fb1, 4, 2);                                          \
    asm volatile("s_waitcnt vmcnt(4)" ::: "memory");                      \
    __builtin_amdgcn_sched_barrier(0);                                    \
    __builtin_amdgcn_s_barrier();                                         \
} while (0)

__global__ __launch_bounds__(512, 2) void gemm256_nt(const u16* __restrict__ A,
                                                     const u16* __restrict__ B,
                                                     const u16* __restrict__ qsig,
                                                     u16* __restrict__ yt) {
    __shared__ u16 L[65536];   // 128 KiB
    int tid = threadIdx.x;
    int lane = tid & 63, wid = tid >> 6;
    int fr = lane & 15, kg = lane >> 4;
    int wr = wid >> 2, wc = wid & 3;
    int bm = blockIdx.x, bn = blockIdx.y;
    const char* LB = (const char*)L;

    // swizzled ds_read column byte offsets (within 128B row) for kk=0,1
    int colx0 = (kg * 16) ^ ((fr & 7) << 4);
    int colx1 = (64 + kg * 16) ^ ((fr & 7) << 4);

    // staging source (inverse-swizzled): row tid>>3 (+64/rnd, +128/half),
    // col elem ((tid&7)^((tid>>3)&7))*8
    int sc = ((tid & 7) ^ ((tid >> 3) & 7)) * 8;
    const u16* sA = A + (size_t)(bm * 256 + (tid >> 3)) * 4096 + sc;
    const u16* sB = B + (size_t)(bn * 256 + (tid >> 3)) * 4096 + sc;

    f32x4 acc[8][4];
#pragma unroll
    for (int m = 0; m < 8; ++m)
#pragma unroll
        for (int n = 0; n < 4; ++n) acc[m][n] = (f32x4){0.f, 0.f, 0.f, 0.f};

    short8 fa[4][2], fb0[2][2], fb1[2][2];

    // prologue: tile0 (4 halves) + tile1's B0, A0; allow tile1's 4 loads in flight
    STAGE_A(0, 0, 0); STAGE_A(0, 1, 0); STAGE_B(0, 0, 0); STAGE_B(0, 1, 0);
    STAGE_B(1, 0, 1); STAGE_A(1, 0, 1);
    asm volatile("s_waitcnt vmcnt(4)" ::: "memory");
    __builtin_amdgcn_sched_barrier(0);
    __builtin_amdgcn_s_barrier();

#pragma unroll 1
    for (int tt = 0; tt < 64; tt += 2) {
        TILE(tt, 0);
        TILE(tt + 1, 1);
    }

    // fused AFT epilogue: yt = sigmoid(Q) * num/den
    int colgb = bn * 256 + wc * 64;
    int row0 = bm * 256 + wr * 128;
    bool isnum = ((fr & 1) == 0);
#pragma unroll
    for (int n = 0; n < 4; ++n) {
        int colg = colgb + n * 16 + fr;
        int b = colg >> 9;
        int f = (colg & 511) >> 1;
#pragma unroll
        for (int m = 0; m < 8; ++m) {
            int tr0 = row0 + m * 16 + kg * 4;
#pragma unroll
            for (int i = 0; i < 4; ++i) {
                float v = acc[m][n][i];
                float other = __shfl_xor(v, 1);
                if (isnum) {
                    size_t idx = ((size_t)(b * 4096 + tr0 + i) << 8) + f;
                    float q = bf2f(qsig[idx]);
                    float r = q * v * __builtin_amdgcn_rcpf(other);
                    yt[idx] = f2bf(r);
                }
            }
        }
    }
}

// ---------------------------------------------------------------------------
// Build Mt flat [4096][T]: row b*512+2f = expK*V feature f, b*512+2f+1 = expK
// ---------------------------------------------------------------------------
__global__ __launch_bounds__(256) void build_mt(const u16* __restrict__ Kraw,
                                                const u16* __restrict__ Vraw,
                                                u16* __restrict__ Mt) {
    __shared__ u16 Ks[64][264];
    __shared__ u16 Vs[64][264];
    __shared__ float part[64][4];
    __shared__ float rmax[64];

    int s0 = blockIdx.x * 64;
    int b = blockIdx.y;
    int tid = threadIdx.x;
    size_t base = ((size_t)b * TT + s0) * FF;

#pragma unroll
    for (int v = 0; v < 8; ++v) {
        int i = v * 256 + tid;
        int row = i >> 5;
        int cb = (i & 31) << 3;
        *(u32x4*)&Ks[row][cb] = *(const u32x4*)(Kraw + base + (size_t)row * FF + cb);
        *(u32x4*)&Vs[row][cb] = *(const u32x4*)(Vraw + base + (size_t)row * FF + cb);
    }
    __syncthreads();
    {
        int row = tid >> 2, p = tid & 3;
        float m = -1e30f;
        for (int c = p * 64; c < p * 64 + 64; ++c) m = fmaxf(m, bf2f(Ks[row][c]));
        part[row][p] = m;
    }
    __syncthreads();
    if (tid < 64)
        rmax[tid] = fmaxf(fmaxf(part[tid][0], part[tid][1]), fmaxf(part[tid][2], part[tid][3]));
    __syncthreads();

    int f = tid >> 5;
    int lane = tid & 31;
    int sl = lane << 1;
    size_t mtb = (size_t)b * 512 * TT;
    for (int fb = 0; fb < 256; fb += 8) {
        int fi = fb + f;
        float ek0 = expf(bf2f(Ks[sl][fi]) - rmax[sl]);
        float ek1 = expf(bf2f(Ks[sl + 1][fi]) - rmax[sl + 1]);
        float nm0 = ek0 * bf2f(Vs[sl][fi]);
        float nm1 = ek1 * bf2f(Vs[sl + 1][fi]);
        unsigned int pn = (unsigned int)f2bf(nm0) | ((unsigned int)f2bf(nm1) << 16);
        unsigned int pd = (unsigned int)f2bf(ek0) | ((unsigned int)f2bf(ek1) << 16);
        *(unsigned int*)(Mt + mtb + (size_t)(2 * fi) * TT + s0 + sl) = pn;
        *(unsigned int*)(Mt + mtb + (size_t)(2 * fi + 1) * TT + s0 + sl) = pd;
    }
}

// ---------------------------------------------------------------------------
extern "C" void kernel_launch(void* const* d_in, const int* in_sizes, int n_in,
                              void* d_out, int out_size, void* d_ws, size_t ws_size,
                              hipStream_t stream) {
    const float* x  = (const float*)d_in[0];
    const float* wq = (const float*)d_in[1];
    const float* bq = (const float*)d_in[2];
    const float* wk = (const float*)d_in[3];
    const float* bk = (const float*)d_in[4];
    const float* wv = (const float*)d_in[5];
    const float* bv = (const float*)d_in[6];
    const float* w  = (const float*)d_in[7];
    const float* wo = (const float*)d_in[8];
    const float* bo = (const float*)d_in[9];

    char* p = (char*)d_ws;
    u16* expw = (u16*)p; p += (size_t)TT * TT * 2;        // 32 MiB
    u16* xbf  = (u16*)p; p += (size_t)BT * FF * 2;        // 16 MiB (reused as yt)
    u16* wqb  = (u16*)p; p += (size_t)FF * FF * 2;
    u16* wkb  = (u16*)p; p += (size_t)FF * FF * 2;
    u16* wvb  = (u16*)p; p += (size_t)FF * FF * 2;
    u16* wob  = (u16*)p; p += (size_t)FF * FF * 2;
    u16* qsig = (u16*)p; p += (size_t)BT * FF * 2;        // 16 MiB
    u16* kraw = (u16*)p; p += (size_t)BT * FF * 2;        // 16 MiB
    u16* vraw = (u16*)p; p += (size_t)BT * FF * 2;        // 16 MiB
    u16* mt   = (u16*)p; p += (size_t)BB * 512 * TT * 2;  // 32 MiB (flat [4096][T])
    u16* yt = xbf;

    expw_kernel<<<TT, 256, 0, stream>>>(w, expw);

    cvt_bf16_kernel<<<(BT * FF / 4 + 255) / 256, 256, 0, stream>>>(x, xbf, BT * FF / 4);
    cvt_bf16_kernel<<<(FF * FF / 4 + 255) / 256, 256, 0, stream>>>(wq, wqb, FF * FF / 4);
    cvt_bf16_kernel<<<(FF * FF / 4 + 255) / 256, 256, 0, stream>>>(wk, wkb, FF * FF / 4);
    cvt_bf16_kernel<<<(FF * FF / 4 + 255) / 256, 256, 0, stream>>>(wv, wvb, FF * FF / 4);
    cvt_bf16_kernel<<<(FF * FF / 4 + 255) / 256, 256, 0, stream>>>(wo, wob, FF * FF / 4);

    dim3 gp(BT / 128, FF / 128, 1);
    gemm_nt<1><<<gp, 256, 0, stream>>>(xbf, wqb, bq, qsig, BT, FF, FF);
    gemm_nt<2><<<gp, 256, 0, stream>>>(xbf, wkb, bk, kraw, BT, FF, FF);
    gemm_nt<2><<<gp, 256, 0, stream>>>(xbf, wvb, bv, vraw, BT, FF, FF);

    build_mt<<<dim3(TT / 64, BB), 256, 0, stream>>>(kraw, vraw, mt);

    // big GEMM + fused AFT epilogue: yt = sigmoid(Q) * (exp_w@(ekV)^T)/(exp_w@ek^T)
    gemm256_nt<<<dim3(16, 16), 512, 0, stream>>>(expw, mt, qsig, yt);

    gemm_nt<0><<<gp, 256, 0, stream>>>(yt, wob, bo, (float*)d_out, BT, FF, FF);
}

// Round 5
// 207.092 us; speedup vs baseline: 1.6496x; 1.1091x over previous
//
#include <hip/hip_runtime.h>
#include <hip/hip_bf16.h>

// Problem constants
#define BB 8
#define TT 4096
#define FF 256
#define BT 32768   // BB*TT

typedef unsigned short u16;
typedef __attribute__((ext_vector_type(8))) short short8;
typedef __attribute__((ext_vector_type(4))) float f32x4;
typedef __attribute__((ext_vector_type(4))) unsigned int u32x4;

static __device__ __forceinline__ float bf2f(u16 u) {
    union { unsigned int i; float f; } v; v.i = ((unsigned int)u) << 16; return v.f;
}
static __device__ __forceinline__ u16 f2bf(float f) {
    union { float f; unsigned int i; } v; v.f = f;
    unsigned int x = v.i;
    return (u16)((x + 0x7fffu + ((x >> 16) & 1u)) >> 16);  // RNE
}

typedef const __attribute__((address_space(1))) void gvoid_t;
typedef __attribute__((address_space(3))) void svoid_t;

// ---------------------------------------------------------------------------
// exp_w: per-row max then exp(w - max) -> bf16 [T][T]
// ---------------------------------------------------------------------------
__global__ __launch_bounds__(256) void expw_kernel(const float* __restrict__ w,
                                                   u16* __restrict__ ew) {
    __shared__ float red[256];
    int row = blockIdx.x;
    int tid = threadIdx.x;
    const float* wr = w + (size_t)row * TT;

    f32x4 vals[4];
    float m = -1e30f;
#pragma unroll
    for (int v = 0; v < 4; ++v) {
        int idx = (v * 256 + tid) * 4;
        vals[v] = *(const f32x4*)(wr + idx);
#pragma unroll
        for (int j = 0; j < 4; ++j) m = fmaxf(m, vals[v][j]);
    }
    red[tid] = m;
    __syncthreads();
    for (int s = 128; s > 0; s >>= 1) {
        if (tid < s) red[tid] = fmaxf(red[tid], red[tid + s]);
        __syncthreads();
    }
    float rm = red[0];
#pragma unroll
    for (int v = 0; v < 4; ++v) {
        int idx = (v * 256 + tid) * 4;
        float e0 = expf(vals[v][0] - rm), e1 = expf(vals[v][1] - rm);
        float e2 = expf(vals[v][2] - rm), e3 = expf(vals[v][3] - rm);
        uint2 pk;
        pk.x = (unsigned int)f2bf(e0) | ((unsigned int)f2bf(e1) << 16);
        pk.y = (unsigned int)f2bf(e2) | ((unsigned int)f2bf(e3) << 16);
        *(uint2*)(ew + (size_t)row * TT + idx) = pk;
    }
}

// ---------------------------------------------------------------------------
// generic f32 -> bf16 cast, 4 elems/thread
// ---------------------------------------------------------------------------
__global__ __launch_bounds__(256) void cvt_bf16_kernel(const float* __restrict__ in,
                                                       u16* __restrict__ out, int n4) {
    int i = blockIdx.x * 256 + threadIdx.x;
    if (i < n4) {
        f32x4 v = ((const f32x4*)in)[i];
        uint2 pk;
        pk.x = (unsigned int)f2bf(v[0]) | ((unsigned int)f2bf(v[1]) << 16);
        pk.y = (unsigned int)f2bf(v[2]) | ((unsigned int)f2bf(v[3]) << 16);
        ((uint2*)out)[i] = pk;
    }
}

// ---------------------------------------------------------------------------
// interleaved K/V weight cast: wkv[2f] = Wk[f], wkv[2f+1] = Wv[f]  (bf16)
// ---------------------------------------------------------------------------
__global__ __launch_bounds__(256) void cvt_wkv_kernel(const float* __restrict__ wk,
                                                      const float* __restrict__ wv,
                                                      u16* __restrict__ wkv) {
    int i = blockIdx.x * 256 + threadIdx.x;
    if (i < FF * FF / 4) {
        int idx = i * 4;
        int f = idx >> 8, c = idx & 255;
        f32x4 a = *(const f32x4*)(wk + idx);
        f32x4 b = *(const f32x4*)(wv + idx);
        uint2 pa, pb;
        pa.x = (unsigned int)f2bf(a[0]) | ((unsigned int)f2bf(a[1]) << 16);
        pa.y = (unsigned int)f2bf(a[2]) | ((unsigned int)f2bf(a[3]) << 16);
        pb.x = (unsigned int)f2bf(b[0]) | ((unsigned int)f2bf(b[1]) << 16);
        pb.y = (unsigned int)f2bf(b[2]) | ((unsigned int)f2bf(b[3]) << 16);
        *(uint2*)(wkv + (size_t)(2 * f) * 256 + c) = pa;
        *(uint2*)(wkv + (size_t)(2 * f + 1) * 256 + c) = pb;
    }
}

// ---------------------------------------------------------------------------
// Small NT GEMM (m97 structure). MODE 0: f32 out; 1: sigmoid->bf16; 2: ->bf16
// ---------------------------------------------------------------------------
template <int MODE>
__global__ __launch_bounds__(256) void gemm_nt(const u16* __restrict__ A,
                                               const u16* __restrict__ Bm,
                                               const float* __restrict__ bias,
                                               void* __restrict__ Call,
                                               int M, int N, int K) {
    __shared__ u16 As[128 * 32];
    __shared__ u16 Bs[128 * 32];

    int tid = threadIdx.x;
    int lane = tid & 63;
    int w = tid >> 6;
    int wr = w >> 1, wc = w & 1;
    int fr = lane & 15, kg = lane >> 4;

    f32x4 acc[4][4];
#pragma unroll
    for (int m = 0; m < 4; ++m)
#pragma unroll
        for (int n = 0; n < 4; ++n) acc[m][n] = (f32x4){0.f, 0.f, 0.f, 0.f};

    int bm = blockIdx.x, bn = blockIdx.y;
    int nk = K >> 5;

    int srow = tid >> 2;
    int schunk = (tid & 3) << 3;
    const u16* aBase = A + (size_t)(bm * 128 + srow) * K + schunk;
    const u16* bBase = Bm + (size_t)(bn * 128 + srow) * K + schunk;
    size_t half = (size_t)64 * K;

    for (int kt = 0; kt < nk; ++kt) {
        __syncthreads();
        int ko = kt << 5;
        __builtin_amdgcn_global_load_lds((gvoid_t*)(aBase + ko), (svoid_t*)&As[tid * 8], 16, 0, 0);
        __builtin_amdgcn_global_load_lds((gvoid_t*)(aBase + half + ko), (svoid_t*)&As[2048 + tid * 8], 16, 0, 0);
        __builtin_amdgcn_global_load_lds((gvoid_t*)(bBase + ko), (svoid_t*)&Bs[tid * 8], 16, 0, 0);
        __builtin_amdgcn_global_load_lds((gvoid_t*)(bBase + half + ko), (svoid_t*)&Bs[2048 + tid * 8], 16, 0, 0);
        __syncthreads();

        short8 af[4], bfr[4];
#pragma unroll
        for (int m = 0; m < 4; ++m)
            af[m] = *(const short8*)&As[(wr * 64 + m * 16 + fr) * 32 + kg * 8];
#pragma unroll
        for (int n = 0; n < 4; ++n)
            bfr[n] = *(const short8*)&Bs[(wc * 64 + n * 16 + fr) * 32 + kg * 8];
#pragma unroll
        for (int m = 0; m < 4; ++m)
#pragma unroll
            for (int n = 0; n < 4; ++n)
                acc[m][n] = __builtin_amdgcn_mfma_f32_16x16x32_bf16(af[m], bfr[n], acc[m][n], 0, 0, 0);
    }

    int row0 = bm * 128 + wr * 64;
    int col0 = bn * 128 + wc * 64;
#pragma unroll
    for (int n = 0; n < 4; ++n) {
        int col = col0 + n * 16 + fr;
        float bv = bias ? bias[col] : 0.0f;
#pragma unroll
        for (int m = 0; m < 4; ++m) {
            int rbase = row0 + m * 16 + kg * 4;
#pragma unroll
            for (int i = 0; i < 4; ++i) {
                float val = acc[m][n][i] + bv;
                size_t idx = (size_t)(rbase + i) * N + col;
                if (MODE == 0)
                    ((float*)Call)[idx] = val;
                else if (MODE == 1)
                    ((u16*)Call)[idx] = f2bf(1.0f / (1.0f + expf(-val)));
                else
                    ((u16*)Call)[idx] = f2bf(val);
            }
        }
    }
}

// ---------------------------------------------------------------------------
// Fused K/V projection + Mt build.
// C[128][512] = x_tile @ wkv^T (+interleaved bias). col 2f = K_f, 2f+1 = V_f.
// Row-max over K (even cols) via masked shfl reduce + LDS cross-wave combine;
// ek = exp(K - rmax); shfl_xor(1) pairs ek with V; writes Mt[4096][T]:
// row b*512+2f = ek*V (num), row b*512+2f+1 = ek (den), col t.
// ---------------------------------------------------------------------------
__global__ __launch_bounds__(512) void kv_mt_kernel(const u16* __restrict__ xbf,
                                                    const u16* __restrict__ wkv,
                                                    const float* __restrict__ bk,
                                                    const float* __restrict__ bv,
                                                    u16* __restrict__ mt) {
    __shared__ u16 As[128 * 32];     // 8 KB
    __shared__ u16 Bs[512 * 32];     // 32 KB
    __shared__ float rmax4[128][4];  // 2 KB

    int tid = threadIdx.x;
    int lane = tid & 63, wid = tid >> 6;
    int fr = lane & 15, kg = lane >> 4;
    int wr = wid >> 2, wc = wid & 3;
    int row0g = blockIdx.x * 128;

    f32x4 acc[4][8];
#pragma unroll
    for (int m = 0; m < 4; ++m)
#pragma unroll
        for (int n = 0; n < 8; ++n) acc[m][n] = (f32x4){0.f, 0.f, 0.f, 0.f};

    const u16* aSrc = xbf + (size_t)(row0g + (tid >> 2)) * 256 + (tid & 3) * 8;
    const u16* bSrc = wkv + (size_t)(tid >> 2) * 256 + (tid & 3) * 8;

    for (int ks = 0; ks < 8; ++ks) {
        __syncthreads();
        __builtin_amdgcn_global_load_lds((gvoid_t*)(aSrc + ks * 32), (svoid_t*)&As[tid * 8], 16, 0, 0);
#pragma unroll
        for (int c = 0; c < 4; ++c)
            __builtin_amdgcn_global_load_lds((gvoid_t*)(bSrc + (size_t)c * 128 * 256 + ks * 32),
                                             (svoid_t*)&Bs[c * 4096 + tid * 8], 16, 0, 0);
        __syncthreads();

        short8 af[4], bfr[8];
#pragma unroll
        for (int m = 0; m < 4; ++m)
            af[m] = *(const short8*)&As[(wr * 64 + m * 16 + fr) * 32 + kg * 8];
#pragma unroll
        for (int n = 0; n < 8; ++n)
            bfr[n] = *(const short8*)&Bs[(wc * 128 + n * 16 + fr) * 32 + kg * 8];
#pragma unroll
        for (int m = 0; m < 4; ++m)
#pragma unroll
            for (int n = 0; n < 8; ++n)
                acc[m][n] = __builtin_amdgcn_mfma_f32_16x16x32_bf16(af[m], bfr[n], acc[m][n], 0, 0, 0);
    }

    int par = fr & 1;   // 0: K (den), 1: V (num)
    // bias
#pragma unroll
    for (int n = 0; n < 8; ++n) {
        int col = wc * 128 + n * 16 + fr;
        int f = col >> 1;
        float bvv = par ? bv[f] : bk[f];
#pragma unroll
        for (int m = 0; m < 4; ++m)
#pragma unroll
            for (int i = 0; i < 4; ++i) acc[m][n][i] += bvv;
    }

    // per-row K max: mask odd lanes, reduce over fr within 16-lane group
    float rmax[4][4];
#pragma unroll
    for (int m = 0; m < 4; ++m)
#pragma unroll
        for (int i = 0; i < 4; ++i) {
            float mx = -1e30f;
#pragma unroll
            for (int n = 0; n < 8; ++n) mx = fmaxf(mx, par ? -1e30f : acc[m][n][i]);
            mx = fmaxf(mx, __shfl_xor(mx, 2));
            mx = fmaxf(mx, __shfl_xor(mx, 4));
            mx = fmaxf(mx, __shfl_xor(mx, 8));
            mx = fmaxf(mx, __shfl_xor(mx, 1));
            rmax[m][i] = mx;
        }
    if (fr == 0) {
#pragma unroll
        for (int m = 0; m < 4; ++m)
#pragma unroll
            for (int i = 0; i < 4; ++i)
                rmax4[wr * 64 + m * 16 + kg * 4 + i][wc] = rmax[m][i];
    }
    __syncthreads();
#pragma unroll
    for (int m = 0; m < 4; ++m)
#pragma unroll
        for (int i = 0; i < 4; ++i) {
            f32x4 r4 = *(const f32x4*)rmax4[wr * 64 + m * 16 + kg * 4 + i];
            rmax[m][i] = fmaxf(fmaxf(r4[0], r4[1]), fmaxf(r4[2], r4[3]));
        }

    // exp + exchange + write Mt
    int b = row0g >> 12;
    int tcb = (row0g & 4095) + wr * 64;
#pragma unroll
    for (int n = 0; n < 8; ++n) {
        int col = wc * 128 + n * 16 + fr;
        int f = col >> 1;
        size_t rowmt = (size_t)(b * 512 + 2 * f + (par ? 0 : 1));
#pragma unroll
        for (int m = 0; m < 4; ++m) {
            int tc = tcb + m * 16 + kg * 4;
            unsigned int w0, w1;
            u16 o[4];
#pragma unroll
            for (int i = 0; i < 4; ++i) {
                float v = acc[m][n][i];
                float ek = expf(v - rmax[m][i]);   // valid on even (K) lanes
                float ekx = __shfl_xor(ek, 1);     // odd lanes receive K's ek
                float outv = par ? (ekx * v) : ek; // odd: num=ek*V; even: den=ek
                o[i] = f2bf(outv);
            }
            w0 = (unsigned int)o[0] | ((unsigned int)o[1] << 16);
            w1 = (unsigned int)o[2] | ((unsigned int)o[3] << 16);
            uint2 pk = {w0, w1};
            *(uint2*)(mt + rowmt * TT + tc) = pk;
        }
    }
}

// ---------------------------------------------------------------------------
// Big 4096^3 NT GEMM (R3-proven 2-phase/BK=32, 4 LDS buffers, counted vmcnt,
// XOR swizzle, setprio) + fused AFT epilogue:
// yt = sigmoid(Q) * num/den via shfl_xor(1) lane pairing.
// ---------------------------------------------------------------------------
#define GLDS(src, eoff) \
    __builtin_amdgcn_global_load_lds((gvoid_t*)(src), (svoid_t*)&L[eoff], 16, 0, 0)

__global__ __launch_bounds__(512, 2) void gemm256_nt(const u16* __restrict__ A,
                                                     const u16* __restrict__ B,
                                                     const u16* __restrict__ qsig,
                                                     u16* __restrict__ yt) {
    __shared__ u16 L[65536];   // 128 KiB: A bufs [0,32768) elems, B bufs [32768,65536)
    const int K = 4096, nt = 128;
    int tid = threadIdx.x;
    int lane = tid & 63, wid = tid >> 6;
    int fr = lane & 15, kg = lane >> 4;
    int wr = wid >> 2, wc = wid & 3;
    int bm = blockIdx.x, bn = blockIdx.y;

    // ds_read base byte offsets within a 16KB buf region (swizzled)
    int xpart = (((fr & 1) << 6) | (kg << 4)) ^ (((fr >> 1) & 7) << 4);
    int aoff = (wr * 64 + (fr >> 1)) * 128 + xpart;
    int boff = (wc * 32 + (fr >> 1)) * 128 + xpart;

    // staging: thread fills phys bytes wid*2048 + lane*16; inverse-swizzled source
    int l8 = lane >> 3;
    int v = (lane & 7) ^ l8;
    int srow = wid * 32 + l8 * 2 + (v >> 2);
    int scol = (v & 3) * 8;
    const u16* sA = A + (size_t)(bm * 256 + srow) * K + scol;
    const u16* sB = B + (size_t)(bn * 256 + srow) * K + scol;
    int dA = (wid * 2048) / 2 + lane * 8;    // elem offset, buf 0, A region
    int dB = dA + 32768;                     // B region

    f32x4 acc[8][4];
#pragma unroll
    for (int m = 0; m < 8; ++m)
#pragma unroll
        for (int n = 0; n < 4; ++n) acc[m][n] = (f32x4){0.f, 0.f, 0.f, 0.f};

    // prologue: stage tiles 0 and 1
#pragma unroll
    for (int tt = 0; tt < 2; ++tt) {
        const u16* a = sA + tt * 32;
        const u16* b = sB + tt * 32;
        int qe = tt * 8192;
        GLDS(a, dA + qe);
        GLDS(a + 16 * K, dA + qe + 512);
        GLDS(b, dB + qe);
        GLDS(b + 16 * K, dB + qe + 512);
    }
    asm volatile("s_waitcnt vmcnt(4)" ::: "memory");
    __builtin_amdgcn_sched_barrier(0);
    __builtin_amdgcn_s_barrier();

    const char* LB = (const char*)L;
#pragma unroll 1
    for (int t = 0; t < nt; ++t) {
        int p = t & 3;
        int q = (t + 2) & 3;
        int ks = (t + 2 < nt) ? t + 2 : 0;
        int abase = p * 16384 + aoff;
        int bbase = 65536 + p * 16384 + boff;

        // ---- phase 1: all ds_reads, stage A(t+2), MFMA n0-1 ----
        short8 af[8], bf4[4];
#pragma unroll
        for (int m = 0; m < 8; ++m) af[m] = *(const short8*)(LB + abase + m * 1024);
#pragma unroll
        for (int n = 0; n < 4; ++n) bf4[n] = *(const short8*)(LB + bbase + n * 1024);
        const u16* a = sA + ks * 32;
        GLDS(a, dA + q * 8192);
        GLDS(a + 16 * K, dA + q * 8192 + 512);
        asm volatile("s_waitcnt lgkmcnt(0)" ::: "memory");
        __builtin_amdgcn_sched_barrier(0);
        __builtin_amdgcn_s_setprio(1);
#pragma unroll
        for (int m = 0; m < 8; ++m)
#pragma unroll
            for (int n = 0; n < 2; ++n)
                acc[m][n] = __builtin_amdgcn_mfma_f32_16x16x32_bf16(af[m], bf4[n], acc[m][n], 0, 0, 0);
        __builtin_amdgcn_s_setprio(0);
        __builtin_amdgcn_s_barrier();

        // ---- phase 2: stage B(t+2), MFMA n2-3, counted vmcnt ----
        const u16* b = sB + ks * 32;
        GLDS(b, dB + q * 8192);
        GLDS(b + 16 * K, dB + q * 8192 + 512);
        __builtin_amdgcn_s_setprio(1);
#pragma unroll
        for (int m = 0; m < 8; ++m)
#pragma unroll
            for (int n = 2; n < 4; ++n)
                acc[m][n] = __builtin_amdgcn_mfma_f32_16x16x32_bf16(af[m], bf4[n], acc[m][n], 0, 0, 0);
        __builtin_amdgcn_s_setprio(0);
        asm volatile("s_waitcnt vmcnt(4)" ::: "memory");   // t+1 fully landed; t+2 in flight
        __builtin_amdgcn_sched_barrier(0);
        __builtin_amdgcn_s_barrier();
    }

    // fused AFT epilogue: yt = sigmoid(Q) * num/den
    int colgb = bn * 256 + wc * 64;
    int row0 = bm * 256 + wr * 128;
    bool isnum = ((fr & 1) == 0);
#pragma unroll
    for (int n = 0; n < 4; ++n) {
        int colg = colgb + n * 16 + fr;
        int b = colg >> 9;
        int f = (colg & 511) >> 1;
#pragma unroll
        for (int m = 0; m < 8; ++m) {
            int tr0 = row0 + m * 16 + kg * 4;
#pragma unroll
            for (int i = 0; i < 4; ++i) {
                float vv = acc[m][n][i];
                float other = __shfl_xor(vv, 1);
                if (isnum) {
                    size_t idx = ((size_t)(b * 4096 + tr0 + i) << 8) + f;
                    float qv = bf2f(qsig[idx]);
                    float r = qv * vv * __builtin_amdgcn_rcpf(other);
                    yt[idx] = f2bf(r);
                }
            }
        }
    }
}

// ---------------------------------------------------------------------------
extern "C" void kernel_launch(void* const* d_in, const int* in_sizes, int n_in,
                              void* d_out, int out_size, void* d_ws, size_t ws_size,
                              hipStream_t stream) {
    const float* x  = (const float*)d_in[0];
    const float* wq = (const float*)d_in[1];
    const float* bq = (const float*)d_in[2];
    const float* wk = (const float*)d_in[3];
    const float* bk = (const float*)d_in[4];
    const float* wv = (const float*)d_in[5];
    const float* bv = (const float*)d_in[6];
    const float* w  = (const float*)d_in[7];
    const float* wo = (const float*)d_in[8];
    const float* bo = (const float*)d_in[9];

    char* p = (char*)d_ws;
    u16* expw = (u16*)p; p += (size_t)TT * TT * 2;        // 32 MiB
    u16* xbf  = (u16*)p; p += (size_t)BT * FF * 2;        // 16 MiB (reused as yt)
    u16* wqb  = (u16*)p; p += (size_t)FF * FF * 2;
    u16* wob  = (u16*)p; p += (size_t)FF * FF * 2;
    u16* wkv  = (u16*)p; p += (size_t)2 * FF * FF * 2;    // interleaved [512][256]
    u16* qsig = (u16*)p; p += (size_t)BT * FF * 2;        // 16 MiB
    u16* mt   = (u16*)p; p += (size_t)BB * 512 * TT * 2;  // 32 MiB (flat [4096][T])
    u16* yt = xbf;

    expw_kernel<<<TT, 256, 0, stream>>>(w, expw);

    cvt_bf16_kernel<<<(BT * FF / 4 + 255) / 256, 256, 0, stream>>>(x, xbf, BT * FF / 4);
    cvt_bf16_kernel<<<(FF * FF / 4 + 255) / 256, 256, 0, stream>>>(wq, wqb, FF * FF / 4);
    cvt_bf16_kernel<<<(FF * FF / 4 + 255) / 256, 256, 0, stream>>>(wo, wob, FF * FF / 4);
    cvt_wkv_kernel<<<(FF * FF / 4 + 255) / 256, 256, 0, stream>>>(wk, wv, wkv);

    dim3 gp(BT / 128, FF / 128, 1);
    gemm_nt<1><<<gp, 256, 0, stream>>>(xbf, wqb, bq, qsig, BT, FF, FF);

    kv_mt_kernel<<<BT / 128, 512, 0, stream>>>(xbf, wkv, bk, bv, mt);

    // big GEMM + fused AFT epilogue
    gemm256_nt<<<dim3(16, 16), 512, 0, stream>>>(expw, mt, qsig, yt);

    gemm_nt<0><<<gp, 256, 0, stream>>>(yt, wob, bo, (float*)d_out, BT, FF, FF);
}

// Round 6
// 187.608 us; speedup vs baseline: 1.8209x; 1.1039x over previous
//
#include <hip/hip_runtime.h>
#include <hip/hip_bf16.h>

// Problem constants
#define BB 8
#define TT 4096
#define FF 256
#define BT 32768   // BB*TT

typedef unsigned short u16;
typedef __attribute__((ext_vector_type(8))) short short8;
typedef __attribute__((ext_vector_type(4))) float f32x4;
typedef __attribute__((ext_vector_type(4))) unsigned int u32x4;

static __device__ __forceinline__ float bf2f(u16 u) {
    union { unsigned int i; float f; } v; v.i = ((unsigned int)u) << 16; return v.f;
}
static __device__ __forceinline__ u16 f2bf(float f) {
    union { float f; unsigned int i; } v; v.f = f;
    unsigned int x = v.i;
    return (u16)((x + 0x7fffu + ((x >> 16) & 1u)) >> 16);  // RNE
}

typedef const __attribute__((address_space(1))) void gvoid_t;
typedef __attribute__((address_space(3))) void svoid_t;

// ---------------------------------------------------------------------------
// exp_w: per-row max then exp(w - max) -> bf16 [T][T]
// ---------------------------------------------------------------------------
__global__ __launch_bounds__(256) void expw_kernel(const float* __restrict__ w,
                                                   u16* __restrict__ ew) {
    __shared__ float red[256];
    int row = blockIdx.x;
    int tid = threadIdx.x;
    const float* wr = w + (size_t)row * TT;

    f32x4 vals[4];
    float m = -1e30f;
#pragma unroll
    for (int v = 0; v < 4; ++v) {
        int idx = (v * 256 + tid) * 4;
        vals[v] = *(const f32x4*)(wr + idx);
#pragma unroll
        for (int j = 0; j < 4; ++j) m = fmaxf(m, vals[v][j]);
    }
    red[tid] = m;
    __syncthreads();
    for (int s = 128; s > 0; s >>= 1) {
        if (tid < s) red[tid] = fmaxf(red[tid], red[tid + s]);
        __syncthreads();
    }
    float rm = red[0];
#pragma unroll
    for (int v = 0; v < 4; ++v) {
        int idx = (v * 256 + tid) * 4;
        float e0 = expf(vals[v][0] - rm), e1 = expf(vals[v][1] - rm);
        float e2 = expf(vals[v][2] - rm), e3 = expf(vals[v][3] - rm);
        uint2 pk;
        pk.x = (unsigned int)f2bf(e0) | ((unsigned int)f2bf(e1) << 16);
        pk.y = (unsigned int)f2bf(e2) | ((unsigned int)f2bf(e3) << 16);
        *(uint2*)(ew + (size_t)row * TT + idx) = pk;
    }
}

// ---------------------------------------------------------------------------
// f32 -> bf16 cast for x
// ---------------------------------------------------------------------------
__global__ __launch_bounds__(256) void cvt_bf16_kernel(const float* __restrict__ in,
                                                       u16* __restrict__ out, int n4) {
    int i = blockIdx.x * 256 + threadIdx.x;
    if (i < n4) {
        f32x4 v = ((const f32x4*)in)[i];
        uint2 pk;
        pk.x = (unsigned int)f2bf(v[0]) | ((unsigned int)f2bf(v[1]) << 16);
        pk.y = (unsigned int)f2bf(v[2]) | ((unsigned int)f2bf(v[3]) << 16);
        ((uint2*)out)[i] = pk;
    }
}

// ---------------------------------------------------------------------------
// merged weight casts: wq->wqb, wo->wob, (wk,wv)->interleaved wkv
// ---------------------------------------------------------------------------
__global__ __launch_bounds__(256) void cvt_weights_kernel(const float* __restrict__ wq,
                                                          const float* __restrict__ wo,
                                                          const float* __restrict__ wk,
                                                          const float* __restrict__ wv,
                                                          u16* __restrict__ wqb,
                                                          u16* __restrict__ wob,
                                                          u16* __restrict__ wkv) {
    int i = blockIdx.x * 256 + threadIdx.x;   // [0, 3*16384)
    int which = i >> 14, j = i & 16383;
    int idx = j * 4;
    if (which == 0) {
        f32x4 v = *(const f32x4*)(wq + idx);
        uint2 pk;
        pk.x = (unsigned int)f2bf(v[0]) | ((unsigned int)f2bf(v[1]) << 16);
        pk.y = (unsigned int)f2bf(v[2]) | ((unsigned int)f2bf(v[3]) << 16);
        *(uint2*)(wqb + idx) = pk;
    } else if (which == 1) {
        f32x4 v = *(const f32x4*)(wo + idx);
        uint2 pk;
        pk.x = (unsigned int)f2bf(v[0]) | ((unsigned int)f2bf(v[1]) << 16);
        pk.y = (unsigned int)f2bf(v[2]) | ((unsigned int)f2bf(v[3]) << 16);
        *(uint2*)(wob + idx) = pk;
    } else {
        int f = idx >> 8, c = idx & 255;
        f32x4 a = *(const f32x4*)(wk + idx);
        f32x4 b = *(const f32x4*)(wv + idx);
        uint2 pa, pb;
        pa.x = (unsigned int)f2bf(a[0]) | ((unsigned int)f2bf(a[1]) << 16);
        pa.y = (unsigned int)f2bf(a[2]) | ((unsigned int)f2bf(a[3]) << 16);
        pb.x = (unsigned int)f2bf(b[0]) | ((unsigned int)f2bf(b[1]) << 16);
        pb.y = (unsigned int)f2bf(b[2]) | ((unsigned int)f2bf(b[3]) << 16);
        *(uint2*)(wkv + (size_t)(2 * f) * 256 + c) = pa;
        *(uint2*)(wkv + (size_t)(2 * f + 1) * 256 + c) = pb;
    }
}

// ---------------------------------------------------------------------------
// Small NT GEMM (m97 structure). MODE 0: f32 out; 1: sigmoid->bf16; 2: ->bf16
// ---------------------------------------------------------------------------
template <int MODE>
__global__ __launch_bounds__(256) void gemm_nt(const u16* __restrict__ A,
                                               const u16* __restrict__ Bm,
                                               const float* __restrict__ bias,
                                               void* __restrict__ Call,
                                               int M, int N, int K) {
    __shared__ u16 As[128 * 32];
    __shared__ u16 Bs[128 * 32];

    int tid = threadIdx.x;
    int lane = tid & 63;
    int w = tid >> 6;
    int wr = w >> 1, wc = w & 1;
    int fr = lane & 15, kg = lane >> 4;

    f32x4 acc[4][4];
#pragma unroll
    for (int m = 0; m < 4; ++m)
#pragma unroll
        for (int n = 0; n < 4; ++n) acc[m][n] = (f32x4){0.f, 0.f, 0.f, 0.f};

    int bm = blockIdx.x, bn = blockIdx.y;
    int nk = K >> 5;

    int srow = tid >> 2;
    int schunk = (tid & 3) << 3;
    const u16* aBase = A + (size_t)(bm * 128 + srow) * K + schunk;
    const u16* bBase = Bm + (size_t)(bn * 128 + srow) * K + schunk;
    size_t half = (size_t)64 * K;

    for (int kt = 0; kt < nk; ++kt) {
        __syncthreads();
        int ko = kt << 5;
        __builtin_amdgcn_global_load_lds((gvoid_t*)(aBase + ko), (svoid_t*)&As[tid * 8], 16, 0, 0);
        __builtin_amdgcn_global_load_lds((gvoid_t*)(aBase + half + ko), (svoid_t*)&As[2048 + tid * 8], 16, 0, 0);
        __builtin_amdgcn_global_load_lds((gvoid_t*)(bBase + ko), (svoid_t*)&Bs[tid * 8], 16, 0, 0);
        __builtin_amdgcn_global_load_lds((gvoid_t*)(bBase + half + ko), (svoid_t*)&Bs[2048 + tid * 8], 16, 0, 0);
        __syncthreads();

        short8 af[4], bfr[4];
#pragma unroll
        for (int m = 0; m < 4; ++m)
            af[m] = *(const short8*)&As[(wr * 64 + m * 16 + fr) * 32 + kg * 8];
#pragma unroll
        for (int n = 0; n < 4; ++n)
            bfr[n] = *(const short8*)&Bs[(wc * 64 + n * 16 + fr) * 32 + kg * 8];
#pragma unroll
        for (int m = 0; m < 4; ++m)
#pragma unroll
            for (int n = 0; n < 4; ++n)
                acc[m][n] = __builtin_amdgcn_mfma_f32_16x16x32_bf16(af[m], bfr[n], acc[m][n], 0, 0, 0);
    }

    int row0 = bm * 128 + wr * 64;
    int col0 = bn * 128 + wc * 64;
#pragma unroll
    for (int n = 0; n < 4; ++n) {
        int col = col0 + n * 16 + fr;
        float bv = bias ? bias[col] : 0.0f;
#pragma unroll
        for (int m = 0; m < 4; ++m) {
            int rbase = row0 + m * 16 + kg * 4;
#pragma unroll
            for (int i = 0; i < 4; ++i) {
                float val = acc[m][n][i] + bv;
                size_t idx = (size_t)(rbase + i) * N + col;
                if (MODE == 0)
                    ((float*)Call)[idx] = val;
                else if (MODE == 1)
                    ((u16*)Call)[idx] = f2bf(1.0f / (1.0f + expf(-val)));
                else
                    ((u16*)Call)[idx] = f2bf(val);
            }
        }
    }
}

// ---------------------------------------------------------------------------
// Fused K/V projection + Mt build (unchanged from R5).
// ---------------------------------------------------------------------------
__global__ __launch_bounds__(512) void kv_mt_kernel(const u16* __restrict__ xbf,
                                                    const u16* __restrict__ wkv,
                                                    const float* __restrict__ bk,
                                                    const float* __restrict__ bv,
                                                    u16* __restrict__ mt) {
    __shared__ u16 As[128 * 32];     // 8 KB
    __shared__ u16 Bs[512 * 32];     // 32 KB
    __shared__ float rmax4[128][4];  // 2 KB

    int tid = threadIdx.x;
    int lane = tid & 63, wid = tid >> 6;
    int fr = lane & 15, kg = lane >> 4;
    int wr = wid >> 2, wc = wid & 3;
    int row0g = blockIdx.x * 128;

    f32x4 acc[4][8];
#pragma unroll
    for (int m = 0; m < 4; ++m)
#pragma unroll
        for (int n = 0; n < 8; ++n) acc[m][n] = (f32x4){0.f, 0.f, 0.f, 0.f};

    const u16* aSrc = xbf + (size_t)(row0g + (tid >> 2)) * 256 + (tid & 3) * 8;
    const u16* bSrc = wkv + (size_t)(tid >> 2) * 256 + (tid & 3) * 8;

    for (int ks = 0; ks < 8; ++ks) {
        __syncthreads();
        __builtin_amdgcn_global_load_lds((gvoid_t*)(aSrc + ks * 32), (svoid_t*)&As[tid * 8], 16, 0, 0);
#pragma unroll
        for (int c = 0; c < 4; ++c)
            __builtin_amdgcn_global_load_lds((gvoid_t*)(bSrc + (size_t)c * 128 * 256 + ks * 32),
                                             (svoid_t*)&Bs[c * 4096 + tid * 8], 16, 0, 0);
        __syncthreads();

        short8 af[4], bfr[8];
#pragma unroll
        for (int m = 0; m < 4; ++m)
            af[m] = *(const short8*)&As[(wr * 64 + m * 16 + fr) * 32 + kg * 8];
#pragma unroll
        for (int n = 0; n < 8; ++n)
            bfr[n] = *(const short8*)&Bs[(wc * 128 + n * 16 + fr) * 32 + kg * 8];
#pragma unroll
        for (int m = 0; m < 4; ++m)
#pragma unroll
            for (int n = 0; n < 8; ++n)
                acc[m][n] = __builtin_amdgcn_mfma_f32_16x16x32_bf16(af[m], bfr[n], acc[m][n], 0, 0, 0);
    }

    int par = fr & 1;   // 0: K (den), 1: V (num)
#pragma unroll
    for (int n = 0; n < 8; ++n) {
        int col = wc * 128 + n * 16 + fr;
        int f = col >> 1;
        float bvv = par ? bv[f] : bk[f];
#pragma unroll
        for (int m = 0; m < 4; ++m)
#pragma unroll
            for (int i = 0; i < 4; ++i) acc[m][n][i] += bvv;
    }

    float rmax[4][4];
#pragma unroll
    for (int m = 0; m < 4; ++m)
#pragma unroll
        for (int i = 0; i < 4; ++i) {
            float mx = -1e30f;
#pragma unroll
            for (int n = 0; n < 8; ++n) mx = fmaxf(mx, par ? -1e30f : acc[m][n][i]);
            mx = fmaxf(mx, __shfl_xor(mx, 2));
            mx = fmaxf(mx, __shfl_xor(mx, 4));
            mx = fmaxf(mx, __shfl_xor(mx, 8));
            mx = fmaxf(mx, __shfl_xor(mx, 1));
            rmax[m][i] = mx;
        }
    if (fr == 0) {
#pragma unroll
        for (int m = 0; m < 4; ++m)
#pragma unroll
            for (int i = 0; i < 4; ++i)
                rmax4[wr * 64 + m * 16 + kg * 4 + i][wc] = rmax[m][i];
    }
    __syncthreads();
#pragma unroll
    for (int m = 0; m < 4; ++m)
#pragma unroll
        for (int i = 0; i < 4; ++i) {
            f32x4 r4 = *(const f32x4*)rmax4[wr * 64 + m * 16 + kg * 4 + i];
            rmax[m][i] = fmaxf(fmaxf(r4[0], r4[1]), fmaxf(r4[2], r4[3]));
        }

    int b = row0g >> 12;
    int tcb = (row0g & 4095) + wr * 64;
#pragma unroll
    for (int n = 0; n < 8; ++n) {
        int col = wc * 128 + n * 16 + fr;
        int f = col >> 1;
        size_t rowmt = (size_t)(b * 512 + 2 * f + (par ? 0 : 1));
#pragma unroll
        for (int m = 0; m < 4; ++m) {
            int tc = tcb + m * 16 + kg * 4;
            u16 o[4];
#pragma unroll
            for (int i = 0; i < 4; ++i) {
                float v = acc[m][n][i];
                float ek = expf(v - rmax[m][i]);
                float ekx = __shfl_xor(ek, 1);
                float outv = par ? (ekx * v) : ek;
                o[i] = f2bf(outv);
            }
            uint2 pk;
            pk.x = (unsigned int)o[0] | ((unsigned int)o[1] << 16);
            pk.y = (unsigned int)o[2] | ((unsigned int)o[3] << 16);
            *(uint2*)(mt + rowmt * TT + tc) = pk;
        }
    }
}

// ---------------------------------------------------------------------------
// Big 4096^3 NT GEMM: BK=64, 2 LDS buffers, ONE barrier + one lgkm-drain pair
// per K-tile, stage-early + late vmcnt(0) (covered by 64-MFMA cluster),
// XOR-swizzled 128B rows, setprio, fused all-lane AFT epilogue.
// LDS: A buf p = bytes [p*32768, +32768); B at +65536. Row = 64 elems = 128B.
// Swizzle: phys_cb = cb ^ ((row&7)<<4). Reads per 16-lane phase: 8 slots x 2
// lanes = 2-way (free, m136).
// ---------------------------------------------------------------------------
#define GLDS(src, eoff) \
    __builtin_amdgcn_global_load_lds((gvoid_t*)(src), (svoid_t*)&L[eoff], 16, 0, 0)

#define STAGE8(P_, KS_) do {                                                   \
    _Pragma("unroll")                                                          \
    for (int i_ = 0; i_ < 4; ++i_) {                                           \
        GLDS(sA + (size_t)i_ * 64 * 4096 + (KS_) * 64,                         \
             (P_) * 16384 + i_ * 4096 + dst);                                  \
        GLDS(sB + (size_t)i_ * 64 * 4096 + (KS_) * 64,                         \
             32768 + (P_) * 16384 + i_ * 4096 + dst);                          \
    }                                                                          \
} while (0)

__global__ __launch_bounds__(512, 2) void gemm256_nt(const u16* __restrict__ A,
                                                     const u16* __restrict__ B,
                                                     const u16* __restrict__ qsig,
                                                     u16* __restrict__ yt) {
    __shared__ u16 L[65536];   // 128 KiB
    const int K = 4096;
    int tid = threadIdx.x;
    int lane = tid & 63, wid = tid >> 6;
    int fr = lane & 15, kg = lane >> 4;
    int wr = wid >> 2, wc = wid & 3;
    int bm = blockIdx.x, bn = blockIdx.y;
    const char* LB = (const char*)L;

    // swizzled in-row byte offsets for kk=0,1
    int x0 = (kg * 16) ^ ((fr & 7) << 4);
    int x1 = (64 + kg * 16) ^ ((fr & 7) << 4);
    int arow = (wr * 128 + fr) * 128;   // + mf*2048
    int brow = (wc * 64 + fr) * 128;    // + nf*2048

    // staging source (inverse swizzle), dest = linear tid*16B per issue
    int scol = ((tid & 7) * 8) ^ (((tid >> 3) & 7) << 3);
    const u16* sA = A + (size_t)(bm * 256 + (tid >> 3)) * K + scol;
    const u16* sB = B + (size_t)(bn * 256 + (tid >> 3)) * K + scol;
    int dst = tid * 8;   // elems

    f32x4 acc[8][4];
#pragma unroll
    for (int m = 0; m < 8; ++m)
#pragma unroll
        for (int n = 0; n < 4; ++n) acc[m][n] = (f32x4){0.f, 0.f, 0.f, 0.f};

    // prologue: stage tile 0 -> buf 0
    STAGE8(0, 0);
    asm volatile("s_waitcnt vmcnt(0)" ::: "memory");
    __builtin_amdgcn_sched_barrier(0);
    __builtin_amdgcn_s_barrier();

#pragma unroll 1
    for (int t = 0; t < 64; ++t) {
        int p = t & 1;
        const char* abase = LB + p * 32768;
        const char* bbase = LB + 65536 + p * 32768;

        short8 bfr[4][2], af[4][2];
#pragma unroll
        for (int nf = 0; nf < 4; ++nf) {
            const char* rb = bbase + brow + nf * 2048;
            bfr[nf][0] = *(const short8*)(rb + x0);
            bfr[nf][1] = *(const short8*)(rb + x1);
        }
#pragma unroll
        for (int mf = 0; mf < 4; ++mf) {
            const char* rb = abase + arow + mf * 2048;
            af[mf][0] = *(const short8*)(rb + x0);
            af[mf][1] = *(const short8*)(rb + x1);
        }
        int ks = (t + 1 < 64) ? t + 1 : 0;
        STAGE8(p ^ 1, ks);
        asm volatile("s_waitcnt lgkmcnt(0)" ::: "memory");
        __builtin_amdgcn_sched_barrier(0);
        __builtin_amdgcn_s_setprio(1);
#pragma unroll
        for (int mf = 0; mf < 4; ++mf)
#pragma unroll
            for (int nf = 0; nf < 4; ++nf) {
                acc[mf][nf] = __builtin_amdgcn_mfma_f32_16x16x32_bf16(af[mf][0], bfr[nf][0], acc[mf][nf], 0, 0, 0);
                acc[mf][nf] = __builtin_amdgcn_mfma_f32_16x16x32_bf16(af[mf][1], bfr[nf][1], acc[mf][nf], 0, 0, 0);
            }
        __builtin_amdgcn_s_setprio(0);
        // second half: rows 4..7
#pragma unroll
        for (int mf = 0; mf < 4; ++mf) {
            const char* rb = abase + arow + (mf + 4) * 2048;
            af[mf][0] = *(const short8*)(rb + x0);
            af[mf][1] = *(const short8*)(rb + x1);
        }
        asm volatile("s_waitcnt lgkmcnt(0)" ::: "memory");
        __builtin_amdgcn_sched_barrier(0);
        __builtin_amdgcn_s_setprio(1);
#pragma unroll
        for (int mf = 0; mf < 4; ++mf)
#pragma unroll
            for (int nf = 0; nf < 4; ++nf) {
                acc[mf + 4][nf] = __builtin_amdgcn_mfma_f32_16x16x32_bf16(af[mf][0], bfr[nf][0], acc[mf + 4][nf], 0, 0, 0);
                acc[mf + 4][nf] = __builtin_amdgcn_mfma_f32_16x16x32_bf16(af[mf][1], bfr[nf][1], acc[mf + 4][nf], 0, 0, 0);
            }
        __builtin_amdgcn_s_setprio(0);
        asm volatile("s_waitcnt vmcnt(0)" ::: "memory");
        __builtin_amdgcn_sched_barrier(0);
        __builtin_amdgcn_s_barrier();
    }

    // fused AFT epilogue: all lanes productive. Even fr: i 0..1; odd fr: i 2..3.
    int colgb = bn * 256 + wc * 64;
    int row0 = bm * 256 + wr * 128;
    int par = fr & 1;
#pragma unroll
    for (int n = 0; n < 4; ++n) {
        int colg = colgb + n * 16 + fr;
        int b = colg >> 9;
        int f = (colg & 511) >> 1;
#pragma unroll
        for (int m = 0; m < 8; ++m) {
            int tr0 = row0 + m * 16 + kg * 4;
            float v0 = acc[m][n][0], v1 = acc[m][n][1];
            float v2 = acc[m][n][2], v3 = acc[m][n][3];
            float o0 = __shfl_xor(v0, 1), o1 = __shfl_xor(v1, 1);
            float o2 = __shfl_xor(v2, 1), o3 = __shfl_xor(v3, 1);
            // even lane: num = own, den = other; odd: num = other, den = own
            float nA = par ? o2 : v0, dA = par ? v2 : o0;   // i = par?2:0
            float nB = par ? o3 : v1, dB = par ? v3 : o1;   // i = par?3:1
            int iA = par ? 2 : 0;
            size_t idxA = ((size_t)(b * 4096 + tr0 + iA) << 8) + f;
            size_t idxB = idxA + 256;
            float qA = bf2f(qsig[idxA]);
            float qB = bf2f(qsig[idxB]);
            yt[idxA] = f2bf(qA * nA * __builtin_amdgcn_rcpf(dA));
            yt[idxB] = f2bf(qB * nB * __builtin_amdgcn_rcpf(dB));
        }
    }
}

// ---------------------------------------------------------------------------
extern "C" void kernel_launch(void* const* d_in, const int* in_sizes, int n_in,
                              void* d_out, int out_size, void* d_ws, size_t ws_size,
                              hipStream_t stream) {
    const float* x  = (const float*)d_in[0];
    const float* wq = (const float*)d_in[1];
    const float* bq = (const float*)d_in[2];
    const float* wk = (const float*)d_in[3];
    const float* bk = (const float*)d_in[4];
    const float* wv = (const float*)d_in[5];
    const float* bv = (const float*)d_in[6];
    const float* w  = (const float*)d_in[7];
    const float* wo = (const float*)d_in[8];
    const float* bo = (const float*)d_in[9];

    char* p = (char*)d_ws;
    u16* expw = (u16*)p; p += (size_t)TT * TT * 2;        // 32 MiB
    u16* xbf  = (u16*)p; p += (size_t)BT * FF * 2;        // 16 MiB (reused as yt)
    u16* wqb  = (u16*)p; p += (size_t)FF * FF * 2;
    u16* wob  = (u16*)p; p += (size_t)FF * FF * 2;
    u16* wkv  = (u16*)p; p += (size_t)2 * FF * FF * 2;    // interleaved [512][256]
    u16* qsig = (u16*)p; p += (size_t)BT * FF * 2;        // 16 MiB
    u16* mt   = (u16*)p; p += (size_t)BB * 512 * TT * 2;  // 32 MiB (flat [4096][T])
    u16* yt = xbf;

    expw_kernel<<<TT, 256, 0, stream>>>(w, expw);

    cvt_bf16_kernel<<<(BT * FF / 4 + 255) / 256, 256, 0, stream>>>(x, xbf, BT * FF / 4);
    cvt_weights_kernel<<<192, 256, 0, stream>>>(wq, wo, wk, wv, wqb, wob, wkv);

    dim3 gp(BT / 128, FF / 128, 1);
    gemm_nt<1><<<gp, 256, 0, stream>>>(xbf, wqb, bq, qsig, BT, FF, FF);

    kv_mt_kernel<<<BT / 128, 512, 0, stream>>>(xbf, wkv, bk, bv, mt);

    // big GEMM + fused AFT epilogue
    gemm256_nt<<<dim3(16, 16), 512, 0, stream>>>(expw, mt, qsig, yt);

    gemm_nt<0><<<gp, 256, 0, stream>>>(yt, wob, bo, (float*)d_out, BT, FF, FF);
}